// Round 1
// baseline (9998.726 us; speedup 1.0000x reference)
//
#include <hip/hip_runtime.h>
#include <math.h>

// Problem dims
#define BB 128
#define SS 512
#define EE 300
#define NFF 100
#define HH 150
#define TP 16   // positions per leaf block
#define TN 16   // nodes per tree block

__device__ __forceinline__ float sigmoidf_(float x) {
    return 1.0f / (1.0f + __expf(-x));
}
__device__ __forceinline__ float tanh_fast(float x) {
    x = fminf(fmaxf(x, -15.0f), 15.0f);
    float e = __expf(2.0f * x);
    return (e - 1.0f) / (e + 1.0f);
}

// Fused: embedding gather -> conv3/4/5 + relu -> [e|cnn] @ Wp.T + bp -> leaf gates -> cell
__global__ __launch_bounds__(256) void k_leaf(
    const int* __restrict__ x, const float* __restrict__ emb,
    const float* __restrict__ w3, const float* __restrict__ b3,
    const float* __restrict__ w4, const float* __restrict__ b4,
    const float* __restrict__ w5, const float* __restrict__ b5,
    const float* __restrict__ Wp, const float* __restrict__ bp,
    const float* __restrict__ Wx, const float* __restrict__ bx,
    float* __restrict__ h0, float* __restrict__ c0)
{
    __shared__ float e_s[TP + 4][301];   // rows s0-2 .. s0+TP+1 (301: stride 13 mod 32, conflict-free)
    __shared__ float cnn_s[TP][301];     // 300 conv features per position
    __shared__ float leaf_s[TP][153];    // 150 leaf values per position

    const int b  = blockIdx.x;
    const int s0 = blockIdx.y * TP;
    const int tid = threadIdx.x;

    // ---- Phase 0: gather embedding rows (float4) ----
    for (int idx = tid; idx < (TP + 4) * 75; idx += 256) {
        int r = idx / 75, q = idx % 75;
        int sp = s0 - 2 + r;
        float4 v = make_float4(0.f, 0.f, 0.f, 0.f);
        if (sp >= 0 && sp < SS) {
            int tok = x[b * SS + sp];
            v = *reinterpret_cast<const float4*>(emb + (size_t)tok * EE + q * 4);
        }
        e_s[r][q * 4 + 0] = v.x;
        e_s[r][q * 4 + 1] = v.y;
        e_s[r][q * 4 + 2] = v.z;
        e_s[r][q * 4 + 3] = v.w;
    }
    __syncthreads();

    const int p  = tid & 15;   // position in tile
    const int fl = tid >> 4;   // lane within feature/hidden group (0..15)

    // ---- Phase 1: convolutions (300 features) ----
    for (int fb = 0; fb < 300; fb += 16) {
        int f = fb + fl;
        if (f < 300) {
            float acc;
            if (f < 100) {                       // conv3: padL=1 -> rows p+1..p+3
                const float* w = w3 + (size_t)f * 900;
                acc = b3[f];
                #pragma unroll 4
                for (int j = 0; j < 300; ++j) {
                    acc += e_s[p + 1][j] * w[j * 3 + 0]
                         + e_s[p + 2][j] * w[j * 3 + 1]
                         + e_s[p + 3][j] * w[j * 3 + 2];
                }
            } else if (f < 200) {                // conv4: padL=1 -> rows p+1..p+4
                const float* w = w4 + (size_t)(f - 100) * 1200;
                acc = b4[f - 100];
                #pragma unroll 4
                for (int j = 0; j < 300; ++j) {
                    float4 wv = *reinterpret_cast<const float4*>(w + j * 4);
                    acc += e_s[p + 1][j] * wv.x
                         + e_s[p + 2][j] * wv.y
                         + e_s[p + 3][j] * wv.z
                         + e_s[p + 4][j] * wv.w;
                }
            } else {                             // conv5: padL=2 -> rows p..p+4
                const float* w = w5 + (size_t)(f - 200) * 1500;
                acc = b5[f - 200];
                #pragma unroll 4
                for (int j = 0; j < 300; ++j) {
                    acc += e_s[p + 0][j] * w[j * 5 + 0]
                         + e_s[p + 1][j] * w[j * 5 + 1]
                         + e_s[p + 2][j] * w[j * 5 + 2]
                         + e_s[p + 3][j] * w[j * 5 + 3]
                         + e_s[p + 4][j] * w[j * 5 + 4];
                }
            }
            cnn_s[p][f] = fmaxf(acc, 0.0f);
        }
    }
    __syncthreads();

    // ---- Phase 2: leaf projection: leaf = [e|cnn] @ Wp.T + bp ----
    for (int hb = 0; hb < HH; hb += 16) {
        int h = hb + fl;
        if (h < HH) {
            const float* wrow = Wp + (size_t)h * 600;
            float acc = bp[h];
            #pragma unroll 4
            for (int j = 0; j < 300; ++j) acc += e_s[p + 2][j] * wrow[j];
            #pragma unroll 4
            for (int j = 0; j < 300; ++j) acc += cnn_s[p][j] * wrow[300 + j];
            leaf_s[p][h] = acc;
        }
    }
    __syncthreads();

    // ---- Phase 3: leaf gates (only i, o, u matter: c = i*u) + cell ----
    const int s = s0 + p;
    for (int hb = 0; hb < HH; hb += 16) {
        int h = hb + fl;
        if (h < HH) {
            float gi = bx[h], go = bx[450 + h], gu = bx[600 + h];
            const float* wi = Wx + (size_t)h * 150;
            const float* wo = Wx + (size_t)(450 + h) * 150;
            const float* wu = Wx + (size_t)(600 + h) * 150;
            #pragma unroll 2
            for (int j = 0; j < 150; ++j) {
                float lv = leaf_s[p][j];
                gi += lv * wi[j];
                go += lv * wo[j];
                gu += lv * wu[j];
            }
            float iv = sigmoidf_(gi);
            float ov = sigmoidf_(go);
            float uv = tanh_fast(gu);
            float cc = iv * uv;
            float hh = ov * tanh_fast(cc);
            h0[((size_t)b * SS + s) * HH + h] = hh;
            c0[((size_t)b * SS + s) * HH + h] = cc;
        }
    }
}

// One tree level: gates = lh@UL.T + rh@UR.T + bx ; c = i*u + fL*lc + fR*rc ; h = o*tanh(c)
__global__ __launch_bounds__(256) void k_tree(
    const float* __restrict__ in_h, const float* __restrict__ in_c,
    float* __restrict__ out_h, float* __restrict__ out_c,
    int n_out,
    const float* __restrict__ UL, const float* __restrict__ UR,
    const float* __restrict__ bx)
{
    __shared__ float lh_s[TN][153], rh_s[TN][153];
    const int b   = blockIdx.x;
    const int m0  = blockIdx.y * TN;
    const int tid = threadIdx.x;
    const int n_in = n_out * 2;

    for (int idx = tid; idx < TN * HH; idx += 256) {
        int p = idx / HH, j = idx % HH;
        int m = m0 + p;
        if (m < n_out) {
            lh_s[p][j] = in_h[((size_t)b * n_in + 2 * m)     * HH + j];
            rh_s[p][j] = in_h[((size_t)b * n_in + 2 * m + 1) * HH + j];
        }
    }
    __syncthreads();

    const int p  = tid & 15;
    const int fl = tid >> 4;
    const int m  = m0 + p;
    if (m >= n_out) return;

    for (int hb = 0; hb < HH; hb += 16) {
        int h = hb + fl;
        if (h < HH) {
            float gi = bx[h], gl = bx[150 + h], gr = bx[300 + h], go = bx[450 + h], gu = bx[600 + h];
            const float* uli = UL + (size_t)h * 150;
            const float* ull = UL + (size_t)(150 + h) * 150;
            const float* ulr = UL + (size_t)(300 + h) * 150;
            const float* ulo = UL + (size_t)(450 + h) * 150;
            const float* ulu = UL + (size_t)(600 + h) * 150;
            const float* uri = UR + (size_t)h * 150;
            const float* url = UR + (size_t)(150 + h) * 150;
            const float* urr = UR + (size_t)(300 + h) * 150;
            const float* uro = UR + (size_t)(450 + h) * 150;
            const float* uru = UR + (size_t)(600 + h) * 150;
            #pragma unroll 2
            for (int j = 0; j < 150; ++j) {
                float lv = lh_s[p][j], rv = rh_s[p][j];
                gi += lv * uli[j] + rv * uri[j];
                gl += lv * ull[j] + rv * url[j];
                gr += lv * ulr[j] + rv * urr[j];
                go += lv * ulo[j] + rv * uro[j];
                gu += lv * ulu[j] + rv * uru[j];
            }
            float iv = sigmoidf_(gi);
            float fL = sigmoidf_(gl);
            float fR = sigmoidf_(gr);
            float ov = sigmoidf_(go);
            float uv = tanh_fast(gu);
            float lc = in_c[((size_t)b * n_in + 2 * m)     * HH + h];
            float rc = in_c[((size_t)b * n_in + 2 * m + 1) * HH + h];
            float cc = iv * uv + fL * lc + fR * rc;
            float hh = ov * tanh_fast(cc);
            out_h[((size_t)b * n_out + m) * HH + h] = hh;
            out_c[((size_t)b * n_out + m) * HH + h] = cc;
        }
    }
}

// Head: z = relu(root@W1.T + b1); out = z@W2.T + b2
__global__ __launch_bounds__(128) void k_head(
    const float* __restrict__ root_h,
    const float* __restrict__ W1, const float* __restrict__ b1,
    const float* __restrict__ W2, const float* __restrict__ b2,
    float* __restrict__ out)
{
    __shared__ float r_s[HH];
    __shared__ float z_s[80];
    const int b = blockIdx.x, tid = threadIdx.x;
    for (int i = tid; i < HH; i += 128) r_s[i] = root_h[(size_t)b * HH + i];
    __syncthreads();
    if (tid < 75) {
        const float* w = W1 + (size_t)tid * 150;
        float acc = b1[tid];
        for (int j = 0; j < 150; ++j) acc += r_s[j] * w[j];
        z_s[tid] = fmaxf(acc, 0.0f);
    }
    __syncthreads();
    if (tid < 3) {
        const float* w = W2 + (size_t)tid * 75;
        float acc = b2[tid];
        for (int j = 0; j < 75; ++j) acc += z_s[j] * w[j];
        out[(size_t)b * 3 + tid] = acc;
    }
}

extern "C" void kernel_launch(void* const* d_in, const int* in_sizes, int n_in,
                              void* d_out, int out_size, void* d_ws, size_t ws_size,
                              hipStream_t stream) {
    const int*   x   = (const int*)  d_in[0];
    const float* emb = (const float*)d_in[1];
    const float* w3  = (const float*)d_in[2];
    const float* b3  = (const float*)d_in[3];
    const float* w4  = (const float*)d_in[4];
    const float* b4  = (const float*)d_in[5];
    const float* w5  = (const float*)d_in[6];
    const float* b5  = (const float*)d_in[7];
    const float* Wp  = (const float*)d_in[8];
    const float* bp  = (const float*)d_in[9];
    const float* Wx  = (const float*)d_in[10];
    const float* bx  = (const float*)d_in[11];
    const float* UL  = (const float*)d_in[12];
    const float* UR  = (const float*)d_in[13];
    const float* W1  = (const float*)d_in[14];
    const float* b1  = (const float*)d_in[15];
    const float* W2  = (const float*)d_in[16];
    const float* b2  = (const float*)d_in[17];
    float* out = (float*)d_out;

    // Workspace layout (floats):
    //   h0,c0: B*S*H each (level-0); h1,c1: B*256*H each (ping-pong)
    float* ws  = (float*)d_ws;
    float* h0  = ws;
    float* c0  = h0 + (size_t)BB * SS * HH;
    float* h1  = c0 + (size_t)BB * SS * HH;
    float* c1  = h1 + (size_t)BB * 256 * HH;

    k_leaf<<<dim3(BB, SS / TP), 256, 0, stream>>>(
        x, emb, w3, b3, w4, b4, w5, b5, Wp, bp, Wx, bx, h0, c0);

    float* hin = h0; float* cin = c0;
    float* hout = h1; float* cout = c1;
    for (int n = 256; n >= 1; n >>= 1) {
        dim3 g(BB, (n + TN - 1) / TN);
        k_tree<<<g, 256, 0, stream>>>(hin, cin, hout, cout, n, UL, UR, bx);
        float* t;
        t = hin; hin = hout; hout = t;
        t = cin; cin = cout; cout = t;
    }
    // result of the last level is in hin after the final swap
    k_head<<<BB, 128, 0, stream>>>(hin, W1, b1, W2, b2, out);
}

// Round 2
// 4647.935 us; speedup vs baseline: 2.1512x; 2.1512x over previous
//
#include <hip/hip_runtime.h>
#include <math.h>

#define BB 128
#define SS 512
#define EE 300
#define HH 150
#define TP 16    // positions per leaf block
#define TN 16    // nodes per tree block
#define E2 304   // padded row stride for e_s / cnn_s (float4-aligned, 300 used)
#define LST 152  // leaf/tree row stride (float2/float4 aligned)
#define GSD 752  // gates row stride

__device__ __forceinline__ float sigmoidf_(float x) {
    return 1.0f / (1.0f + __expf(-x));
}
__device__ __forceinline__ float tanh_fast(float x) {
    x = fminf(fmaxf(x, -15.0f), 15.0f);
    float e = __expf(2.0f * x);
    return (e - 1.0f) / (e + 1.0f);
}

// Build unified 5-tap conv weights: w5u[f][j][t], f in [0,300), t in [0,5)
//   conv3 (pad 1,1): taps t=1..3 ; conv4 (pad 1,2): taps t=1..4 ; conv5 (pad 2,2): taps t=0..4
// Output position p uses e rows (p + t) of a window starting at s0-2.
__global__ __launch_bounds__(256) void k_prep(
    const float* __restrict__ w3, const float* __restrict__ b3,
    const float* __restrict__ w4, const float* __restrict__ b4,
    const float* __restrict__ w5, const float* __restrict__ b5,
    float* __restrict__ w5u, float* __restrict__ bcat)
{
    int idx = blockIdx.x * 256 + threadIdx.x;
    if (idx < 300 * 1500) {
        int f = idx / 1500, r = idx - f * 1500;
        int j = r / 5, t = r - j * 5;
        float v = 0.0f;
        if (f < 100)        { if (t >= 1 && t <= 3) v = w3[f * 900 + j * 3 + (t - 1)]; }
        else if (f < 200)   { if (t >= 1)           v = w4[(f - 100) * 1200 + j * 4 + (t - 1)]; }
        else                {                       v = w5[(f - 200) * 1500 + j * 5 + t]; }
        w5u[idx] = v;
    }
    if (idx < 300)
        bcat[idx] = (idx < 100) ? b3[idx] : (idx < 200 ? b4[idx - 100] : b5[idx - 200]);
}

// Fused leaf: gather -> unified conv (relu) -> leaf projection -> leaf gates -> cell
__global__ __launch_bounds__(384) void k_leaf(
    const int* __restrict__ x, const float* __restrict__ emb,
    const float* __restrict__ w5u, const float* __restrict__ bcat,
    const float* __restrict__ Wp, const float* __restrict__ bp,
    const float* __restrict__ Wx, const float* __restrict__ bx,
    float* __restrict__ h0, float* __restrict__ c0)
{
    __shared__ float e_s[TP + 4][E2];
    __shared__ float cnn_s[TP][E2];
    __shared__ float leaf_s[TP][LST];
    __shared__ float tmp_s[TP][LST];

    const int b   = blockIdx.x;
    const int s0  = blockIdx.y * TP;
    const int tid = threadIdx.x;

    // ---- phase 0: gather 20 embedding rows ----
    for (int idx = tid; idx < 20 * 75; idx += 384) {
        int r = idx / 75, q = idx - r * 75;
        int sp = s0 - 2 + r;
        float4 v = make_float4(0.f, 0.f, 0.f, 0.f);
        if (sp >= 0 && sp < SS) {
            int tok = x[b * SS + sp];
            v = *reinterpret_cast<const float4*>(emb + (size_t)tok * EE + q * 4);
        }
        *reinterpret_cast<float4*>(&e_s[r][q * 4]) = v;
    }
    __syncthreads();

    // ---- phase 1: unified 5-tap conv; thread = feature, 16 position-accumulators ----
    if (tid < 300) {
        const float* wrow = w5u + tid * 1500;   // [j][t] flat, contiguous
        float bias = bcat[tid];
        float acc[TP];
        #pragma unroll
        for (int m = 0; m < TP; ++m) acc[m] = bias;
        for (int j = 0; j < 300; j += 2) {
            const float* wp_ = wrow + j * 5;
            float2 wa = *(const float2*)(wp_ + 0);  // (j,0) (j,1)
            float2 wb = *(const float2*)(wp_ + 2);  // (j,2) (j,3)
            float2 wc = *(const float2*)(wp_ + 4);  // (j,4) (j+1,0)
            float2 wd = *(const float2*)(wp_ + 6);  // (j+1,1) (j+1,2)
            float2 we = *(const float2*)(wp_ + 8);  // (j+1,3) (j+1,4)
            float2 er[20];
            #pragma unroll
            for (int r = 0; r < 20; ++r) er[r] = *(const float2*)(&e_s[r][j]);  // broadcast
            #pragma unroll
            for (int m = 0; m < TP; ++m) {
                acc[m] += er[m + 0].x * wa.x + er[m + 1].x * wa.y + er[m + 2].x * wb.x
                        + er[m + 3].x * wb.y + er[m + 4].x * wc.x
                        + er[m + 0].y * wc.y + er[m + 1].y * wd.x + er[m + 2].y * wd.y
                        + er[m + 3].y * we.x + er[m + 4].y * we.y;
            }
        }
        #pragma unroll
        for (int m = 0; m < TP; ++m) cnn_s[m][tid] = fmaxf(acc[m], 0.0f);
    }
    __syncthreads();

    // ---- phase 2: leaf projection, split e-half / cnn-half across lane groups (branchless) ----
    float acc2[TP];
    #pragma unroll
    for (int m = 0; m < TP; ++m) acc2[m] = 0.0f;
    if (tid < 300) {
        const int part = (tid >= 150);
        const int h    = tid - part * 150;
        const float* wrow = Wp + h * 600 + part * 300;
        const float* srow = part ? &cnn_s[0][0] : &e_s[2][0];   // both stride E2
        for (int j = 0; j < 300; j += 4) {
            float4 w = *(const float4*)(wrow + j);
            #pragma unroll
            for (int m = 0; m < TP; ++m) {
                float4 v = *(const float4*)(srow + m * E2 + j);  // broadcast
                acc2[m] += v.x * w.x + v.y * w.y + v.z * w.z + v.w * w.w;
            }
        }
        if (part) {
            #pragma unroll
            for (int m = 0; m < TP; ++m) tmp_s[m][h] = acc2[m];
        }
    }
    __syncthreads();
    if (tid < 150) {
        float bv = bp[tid];
        #pragma unroll
        for (int m = 0; m < TP; ++m) leaf_s[m][tid] = acc2[m] + tmp_s[m][tid] + bv;
    }
    __syncthreads();

    // ---- phase 3: leaf gates (i,o,u) + cell; thread = h, 16 positions ----
    if (tid < 150) {
        const int h = tid;
        float ai[TP], ao[TP], au[TP];
        float bi = bx[h], bo = bx[450 + h], bu = bx[600 + h];
        #pragma unroll
        for (int m = 0; m < TP; ++m) { ai[m] = bi; ao[m] = bo; au[m] = bu; }
        const float* wi = Wx + (size_t)h * 150;
        const float* wo = Wx + (size_t)(450 + h) * 150;
        const float* wu = Wx + (size_t)(600 + h) * 150;
        for (int j = 0; j < 150; j += 2) {
            float2 wiv = *(const float2*)(wi + j);
            float2 wov = *(const float2*)(wo + j);
            float2 wuv = *(const float2*)(wu + j);
            #pragma unroll
            for (int m = 0; m < TP; ++m) {
                float2 lv = *(const float2*)(&leaf_s[m][j]);   // broadcast
                ai[m] += lv.x * wiv.x + lv.y * wiv.y;
                ao[m] += lv.x * wov.x + lv.y * wov.y;
                au[m] += lv.x * wuv.x + lv.y * wuv.y;
            }
        }
        #pragma unroll
        for (int m = 0; m < TP; ++m) {
            float iv = sigmoidf_(ai[m]);
            float ov = sigmoidf_(ao[m]);
            float uv = tanh_fast(au[m]);
            float cc = iv * uv;
            float hh = ov * tanh_fast(cc);
            size_t o = ((size_t)b * SS + s0 + m) * HH + h;
            h0[o] = hh;
            c0[o] = cc;
        }
    }
}

// One tree level: 16 nodes/block; thread computes 2 gate-rows for all 16 nodes,
// gate buffer in LDS, then cell-combine pass.
__global__ __launch_bounds__(384) void k_tree(
    const float* __restrict__ in_h, const float* __restrict__ in_c,
    float* __restrict__ out_h, float* __restrict__ out_c,
    int n_out,
    const float* __restrict__ UL, const float* __restrict__ UR,
    const float* __restrict__ bx)
{
    __shared__ float lh_s[TN][LST], rh_s[TN][LST];
    __shared__ float g_s[TN][GSD];

    const int b    = blockIdx.x;
    const int m0   = blockIdx.y * TN;
    const int tid  = threadIdx.x;
    const int n_in = n_out * 2;
    const int nv   = (n_out - m0 < TN) ? (n_out - m0) : TN;

    for (int idx = tid; idx < nv * HH; idx += 384) {
        int p = idx / HH, j = idx - p * HH;
        size_t base = ((size_t)b * n_in + 2 * (m0 + p)) * HH + j;
        lh_s[p][j] = in_h[base];
        rh_s[p][j] = in_h[base + HH];
    }
    __syncthreads();

    {
        const int o1 = tid;
        const int o2t = tid + 384;
        const bool has2 = (o2t < 750);
        const int o2 = has2 ? o2t : 0;
        float a1[TN], a2[TN];
        float b1v = (o1 < 750) ? bx[o1] : 0.0f;
        float b2v = bx[o2];
        #pragma unroll
        for (int m = 0; m < TN; ++m) { a1[m] = b1v; a2[m] = b2v; }
        if (o1 < 750) {
            const float* ul1 = UL + (size_t)o1 * 150;
            const float* ur1 = UR + (size_t)o1 * 150;
            const float* ul2 = UL + (size_t)o2 * 150;
            const float* ur2 = UR + (size_t)o2 * 150;
            for (int j = 0; j < 150; j += 2) {
                float2 wl1 = *(const float2*)(ul1 + j);
                float2 wr1 = *(const float2*)(ur1 + j);
                float2 wl2 = *(const float2*)(ul2 + j);
                float2 wr2 = *(const float2*)(ur2 + j);
                #pragma unroll
                for (int m = 0; m < TN; ++m) {
                    float2 lv = *(const float2*)(&lh_s[m][j]);   // broadcast
                    float2 rv = *(const float2*)(&rh_s[m][j]);   // broadcast
                    a1[m] += lv.x * wl1.x + lv.y * wl1.y + rv.x * wr1.x + rv.y * wr1.y;
                    a2[m] += lv.x * wl2.x + lv.y * wl2.y + rv.x * wr2.x + rv.y * wr2.y;
                }
            }
            #pragma unroll
            for (int m = 0; m < TN; ++m) {
                g_s[m][o1] = a1[m];
                if (has2) g_s[m][o2t] = a2[m];
            }
        }
    }
    __syncthreads();

    for (int idx = tid; idx < nv * HH; idx += 384) {
        int m = idx / HH, h = idx - m * HH;
        float gi = g_s[m][h];
        float gl = g_s[m][150 + h];
        float gr = g_s[m][300 + h];
        float go = g_s[m][450 + h];
        float gu = g_s[m][600 + h];
        float iv = sigmoidf_(gi);
        float fL = sigmoidf_(gl);
        float fR = sigmoidf_(gr);
        float ov = sigmoidf_(go);
        float uv = tanh_fast(gu);
        size_t lbase = ((size_t)b * n_in + 2 * (m0 + m)) * HH + h;
        float lc = in_c[lbase];
        float rc = in_c[lbase + HH];
        float cc = iv * uv + fL * lc + fR * rc;
        size_t obase = ((size_t)b * n_out + m0 + m) * HH + h;
        out_h[obase] = ov * tanh_fast(cc);
        out_c[obase] = cc;
    }
}

// Head: z = relu(root@W1.T + b1); out = z@W2.T + b2
__global__ __launch_bounds__(128) void k_head(
    const float* __restrict__ root_h,
    const float* __restrict__ W1, const float* __restrict__ b1,
    const float* __restrict__ W2, const float* __restrict__ b2,
    float* __restrict__ out)
{
    __shared__ float r_s[HH];
    __shared__ float z_s[80];
    const int b = blockIdx.x, tid = threadIdx.x;
    for (int i = tid; i < HH; i += 128) r_s[i] = root_h[(size_t)b * HH + i];
    __syncthreads();
    if (tid < 75) {
        const float* w = W1 + (size_t)tid * 150;
        float acc = b1[tid];
        for (int j = 0; j < 150; ++j) acc += r_s[j] * w[j];
        z_s[tid] = fmaxf(acc, 0.0f);
    }
    __syncthreads();
    if (tid < 3) {
        const float* w = W2 + (size_t)tid * 75;
        float acc = b2[tid];
        for (int j = 0; j < 75; ++j) acc += z_s[j] * w[j];
        out[(size_t)b * 3 + tid] = acc;
    }
}

extern "C" void kernel_launch(void* const* d_in, const int* in_sizes, int n_in,
                              void* d_out, int out_size, void* d_ws, size_t ws_size,
                              hipStream_t stream) {
    const int*   x   = (const int*)  d_in[0];
    const float* emb = (const float*)d_in[1];
    const float* w3  = (const float*)d_in[2];
    const float* b3  = (const float*)d_in[3];
    const float* w4  = (const float*)d_in[4];
    const float* b4  = (const float*)d_in[5];
    const float* w5  = (const float*)d_in[6];
    const float* b5  = (const float*)d_in[7];
    const float* Wp  = (const float*)d_in[8];
    const float* bp  = (const float*)d_in[9];
    const float* Wx  = (const float*)d_in[10];
    const float* bx  = (const float*)d_in[11];
    const float* UL  = (const float*)d_in[12];
    const float* UR  = (const float*)d_in[13];
    const float* W1  = (const float*)d_in[14];
    const float* b1  = (const float*)d_in[15];
    const float* W2  = (const float*)d_in[16];
    const float* b2  = (const float*)d_in[17];
    float* out = (float*)d_out;

    // Workspace (floats): w5u 450000 | bcat 300 (+4 pad) | h0,c0 B*S*H | h1,c1 B*256*H
    float* ws   = (float*)d_ws;
    float* w5u  = ws;
    float* bcat = ws + 450000;
    float* h0   = ws + 450304;
    float* c0   = h0 + (size_t)BB * SS * HH;
    float* h1   = c0 + (size_t)BB * SS * HH;
    float* c1   = h1 + (size_t)BB * 256 * HH;

    k_prep<<<(450000 + 255) / 256, 256, 0, stream>>>(w3, b3, w4, b4, w5, b5, w5u, bcat);

    k_leaf<<<dim3(BB, SS / TP), 384, 0, stream>>>(
        x, emb, w5u, bcat, Wp, bp, Wx, bx, h0, c0);

    float* hin = h0; float* cin = c0;
    float* hout = h1; float* cout = c1;
    for (int n = 256; n >= 1; n >>= 1) {
        dim3 g(BB, (n + TN - 1) / TN);
        k_tree<<<g, 384, 0, stream>>>(hin, cin, hout, cout, n, UL, UR, bx);
        float* t;
        t = hin; hin = hout; hout = t;
        t = cin; cin = cout; cout = t;
    }
    k_head<<<BB, 128, 0, stream>>>(hin, W1, b1, W2, b2, out);
}

// Round 3
// 3044.202 us; speedup vs baseline: 3.2845x; 1.5268x over previous
//
#include <hip/hip_runtime.h>
#include <math.h>

#define BB 128
#define SS 512
#define EE 300
#define HH 150
#define TP 16
#define TN 16
#define E2 304   // e_s/cnn_s row stride (floats)
#define LST 152  // leaf/tree row stride
#define GS 752   // gate buffer row stride
#define UST 768  // transposed UL/UR row stride (cols 750..767 zero)

// ws offsets (floats)
#define OFF_W5UT  0
#define OFF_BCAT  450000
#define OFF_WPT   450304
#define OFF_WXT   540304
#define OFF_ULT   607808
#define OFF_URT   723008
#define OFF_H0    838208
#define SZ_HC0    (BB * SS * HH)
#define OFF_C0    (OFF_H0 + SZ_HC0)
#define OFF_H1    (OFF_C0 + SZ_HC0)
#define SZ_HC1    (BB * 256 * HH)
#define OFF_C1    (OFF_H1 + SZ_HC1)

__device__ __forceinline__ float sigmoidf_(float x) {
    return 1.0f / (1.0f + __expf(-x));
}
__device__ __forceinline__ float tanh_fast(float x) {
    x = fminf(fmaxf(x, -15.0f), 15.0f);
    float e = __expf(2.0f * x);
    return (e - 1.0f) / (e + 1.0f);
}

// One-time weight reshuffles, all writes coalesced:
//  w5u_T[(j*5+t)*300 + f]      unified 5-tap conv weight (zero-padded taps)
//  WpT  [j*300 + c]            = Wp[c>>1][j + (c&1)*300]   (c = lane id in k_leaf ph2)
//  WxT  [(j*3+g)*150 + h]      = Wx[{0,450,600}[g] + h][j] (gates i,o,u)
//  ULT/URT[j*768 + o]          = UL/UR[o][j], cols >=750 zero
__global__ __launch_bounds__(256) void k_prep(
    const float* __restrict__ w3, const float* __restrict__ b3,
    const float* __restrict__ w4, const float* __restrict__ b4,
    const float* __restrict__ w5, const float* __restrict__ b5,
    const float* __restrict__ Wp, const float* __restrict__ Wx,
    const float* __restrict__ UL, const float* __restrict__ UR,
    float* __restrict__ ws)
{
    int idx = blockIdx.x * 256 + threadIdx.x;
    if (idx < 450000) {
        int row = idx / 300, f = idx - row * 300;
        int j = row / 5, t = row - j * 5;
        float v = 0.0f;
        if (f < 100)      { if (t >= 1 && t <= 3) v = w3[f * 900 + j * 3 + (t - 1)]; }
        else if (f < 200) { if (t >= 1)           v = w4[(f - 100) * 1200 + j * 4 + (t - 1)]; }
        else              {                       v = w5[(f - 200) * 1500 + j * 5 + t]; }
        ws[OFF_W5UT + idx] = v;
    } else if (idx < 450300) {
        int f = idx - 450000;
        ws[OFF_BCAT + f] = (f < 100) ? b3[f] : (f < 200 ? b4[f - 100] : b5[f - 200]);
    } else if (idx < 540300) {
        int i2 = idx - 450300;
        int j = i2 / 300, c = i2 - j * 300;
        ws[OFF_WPT + i2] = Wp[(c >> 1) * 600 + j + (c & 1) * 300];
    } else if (idx < 607800) {
        int i2 = idx - 540300;
        int row = i2 / 150, h = i2 - row * 150;
        int j = row / 3, g = row - j * 3;
        int src = (g == 0 ? 0 : (g == 1 ? 450 : 600)) + h;
        ws[OFF_WXT + i2] = Wx[src * 150 + j];
    } else if (idx < 723000) {
        int i2 = idx - 607800;
        int j = i2 / UST, o = i2 - j * UST;
        ws[OFF_ULT + i2] = (o < 750) ? UL[o * 150 + j] : 0.0f;
    } else if (idx < 838200) {
        int i2 = idx - 723000;
        int j = i2 / UST, o = i2 - j * UST;
        ws[OFF_URT + i2] = (o < 750) ? UR[o * 150 + j] : 0.0f;
    }
}

// Fused leaf: gather -> unified conv(relu) -> leaf proj -> leaf gates -> cell
__global__ __launch_bounds__(320, 4) void k_leaf(
    const int* __restrict__ x, const float* __restrict__ emb,
    const float* __restrict__ w5u_T, const float* __restrict__ bcat,
    const float* __restrict__ WpT, const float* __restrict__ WxT,
    const float* __restrict__ bp, const float* __restrict__ bx,
    float* __restrict__ h0, float* __restrict__ c0)
{
    __shared__ float e_s[TP + 4][E2];
    __shared__ float cnn_s[TP][E2];
    __shared__ float leaf_s[TP][LST];

    const int b   = blockIdx.x;
    const int s0  = blockIdx.y * TP;
    const int tid = threadIdx.x;

    // phase 0: gather 20 embedding rows
    for (int idx = tid; idx < 20 * 75; idx += 320) {
        int r = idx / 75, q = idx - r * 75;
        int sp = s0 - 2 + r;
        float4 v = make_float4(0.f, 0.f, 0.f, 0.f);
        if (sp >= 0 && sp < SS) {
            int tok = x[b * SS + sp];
            v = *reinterpret_cast<const float4*>(emb + (size_t)tok * EE + q * 4);
        }
        *reinterpret_cast<float4*>(&e_s[r][q * 4]) = v;
    }
    __syncthreads();

    // phase 1: conv — thread = feature (coalesced weight columns), 16 position accs
    if (tid < 300) {
        const float* wq = w5u_T + tid;
        float bias = bcat[tid];
        float acc[TP];
        #pragma unroll
        for (int m = 0; m < TP; ++m) acc[m] = bias;
        for (int j = 0; j < 300; j += 2) {
            const float* wr = wq + j * 1500;
            float wa0 = wr[0],    wa1 = wr[300],  wa2 = wr[600],  wa3 = wr[900],  wa4 = wr[1200];
            float wb0 = wr[1500], wb1 = wr[1800], wb2 = wr[2100], wb3 = wr[2400], wb4 = wr[2700];
            float2 er[20];
            #pragma unroll
            for (int r = 0; r < 20; ++r) er[r] = *(const float2*)(&e_s[r][j]);  // broadcast
            #pragma unroll
            for (int m = 0; m < TP; ++m) {
                acc[m] += er[m + 0].x * wa0 + er[m + 1].x * wa1 + er[m + 2].x * wa2
                        + er[m + 3].x * wa3 + er[m + 4].x * wa4
                        + er[m + 0].y * wb0 + er[m + 1].y * wb1 + er[m + 2].y * wb2
                        + er[m + 3].y * wb3 + er[m + 4].y * wb4;
            }
        }
        #pragma unroll
        for (int m = 0; m < TP; ++m) cnn_s[m][tid] = fmaxf(acc[m], 0.0f);
    }
    __syncthreads();

    // phase 2: leaf projection; lane pair (2h, 2h+1) covers e-half / cnn-half
    if (tid < 300) {
        const int h = tid >> 1, part = tid & 1;
        const float* srow = part ? &cnn_s[0][0] : &e_s[2][0];   // both stride E2
        const float* wcol = WpT + tid;
        float acc2[TP];
        #pragma unroll
        for (int m = 0; m < TP; ++m) acc2[m] = 0.0f;
        for (int j = 0; j < 300; j += 4) {
            float w0 = wcol[j * 300], w1 = wcol[(j + 1) * 300];
            float w2 = wcol[(j + 2) * 300], w3v = wcol[(j + 3) * 300];
            #pragma unroll
            for (int m = 0; m < TP; ++m) {
                float4 v = *(const float4*)(srow + m * E2 + j);  // broadcast
                acc2[m] += v.x * w0 + v.y * w1 + v.z * w2 + v.w * w3v;
            }
        }
        float bv = bp[h];
        #pragma unroll
        for (int m = 0; m < TP; ++m) {
            float other = __shfl_xor(acc2[m], 1);
            if (!part) leaf_s[m][h] = acc2[m] + other + bv;
        }
    }
    __syncthreads();

    // phase 3: leaf gates (i,o,u) + cell; thread = h (coalesced WxT columns)
    if (tid < 150) {
        const int h = tid;
        const float* wc = WxT + h;
        float ai[TP], ao[TP], au[TP];
        float bi = bx[h], bo = bx[450 + h], bu = bx[600 + h];
        #pragma unroll
        for (int m = 0; m < TP; ++m) { ai[m] = bi; ao[m] = bo; au[m] = bu; }
        for (int j = 0; j < 150; j += 2) {
            const float* wr = wc + j * 450;
            float wi0 = wr[0],   wo0 = wr[150], wu0 = wr[300];
            float wi1 = wr[450], wo1 = wr[600], wu1 = wr[750];
            #pragma unroll
            for (int m = 0; m < TP; ++m) {
                float2 lv = *(const float2*)(&leaf_s[m][j]);   // broadcast
                ai[m] += lv.x * wi0 + lv.y * wi1;
                ao[m] += lv.x * wo0 + lv.y * wo1;
                au[m] += lv.x * wu0 + lv.y * wu1;
            }
        }
        #pragma unroll
        for (int m = 0; m < TP; ++m) {
            float iv = sigmoidf_(ai[m]);
            float ov = sigmoidf_(ao[m]);
            float uv = tanh_fast(au[m]);
            float cc = iv * uv;
            float hh = ov * tanh_fast(cc);
            size_t o = ((size_t)b * SS + s0 + m) * HH + h;
            h0[o] = hh;
            c0[o] = cc;
        }
    }
}

// One tree level (n_out multiple of 16): transposed-U coalesced gate GEMM + cell
__global__ __launch_bounds__(384) void k_tree(
    const float* __restrict__ in_h, const float* __restrict__ in_c,
    float* __restrict__ out_h, float* __restrict__ out_c,
    int n_out,
    const float* __restrict__ ULT, const float* __restrict__ URT,
    const float* __restrict__ bx)
{
    __shared__ float lh_s[TN][LST], rh_s[TN][LST];
    __shared__ float g_s[TN][GS];

    const int b    = blockIdx.x;
    const int m0   = blockIdx.y * TN;
    const int tid  = threadIdx.x;
    const int n_in = n_out * 2;

    for (int idx = tid; idx < TN * HH; idx += 384) {
        int p = idx / HH, j = idx - p * HH;
        size_t base = ((size_t)b * n_in + 2 * (m0 + p)) * HH + j;
        lh_s[p][j] = in_h[base];
        rh_s[p][j] = in_h[base + HH];
    }
    __syncthreads();

    {
        const int o1 = tid, o2 = tid + 384;
        float a1[TN], a2[TN];
        float b1v = bx[o1];
        float b2v = (o2 < 750) ? bx[o2] : 0.0f;
        #pragma unroll
        for (int m = 0; m < TN; ++m) { a1[m] = b1v; a2[m] = b2v; }
        const float* ul1 = ULT + o1; const float* ur1 = URT + o1;
        const float* ul2 = ULT + o2; const float* ur2 = URT + o2;
        for (int j = 0; j < 150; j += 2) {
            int r0 = j * UST, r1 = (j + 1) * UST;
            float wl1a = ul1[r0], wl1b = ul1[r1];
            float wr1a = ur1[r0], wr1b = ur1[r1];
            float wl2a = ul2[r0], wl2b = ul2[r1];
            float wr2a = ur2[r0], wr2b = ur2[r1];
            #pragma unroll
            for (int m = 0; m < TN; ++m) {
                float2 lv = *(const float2*)(&lh_s[m][j]);   // broadcast
                float2 rv = *(const float2*)(&rh_s[m][j]);   // broadcast
                a1[m] += lv.x * wl1a + lv.y * wl1b + rv.x * wr1a + rv.y * wr1b;
                a2[m] += lv.x * wl2a + lv.y * wl2b + rv.x * wr2a + rv.y * wr2b;
            }
        }
        #pragma unroll
        for (int m = 0; m < TN; ++m) {
            g_s[m][o1] = a1[m];
            if (o2 < 750) g_s[m][o2] = a2[m];
        }
    }
    __syncthreads();

    for (int idx = tid; idx < TN * HH; idx += 384) {
        int m = idx / HH, h = idx - m * HH;
        float iv = sigmoidf_(g_s[m][h]);
        float fL = sigmoidf_(g_s[m][150 + h]);
        float fR = sigmoidf_(g_s[m][300 + h]);
        float ov = sigmoidf_(g_s[m][450 + h]);
        float uv = tanh_fast(g_s[m][600 + h]);
        size_t lbase = ((size_t)b * n_in + 2 * (m0 + m)) * HH + h;
        float cc = iv * uv + fL * in_c[lbase] + fR * in_c[lbase + HH];
        size_t obase = ((size_t)b * n_out + m0 + m) * HH + h;
        out_h[obase] = ov * tanh_fast(cc);
        out_c[obase] = cc;
    }
}

// Fused tail: levels n=16..1 entirely in LDS (input = 32-node level), then head MLP
__global__ __launch_bounds__(384) void k_tail(
    const float* __restrict__ in_h, const float* __restrict__ in_c,
    const float* __restrict__ ULT, const float* __restrict__ URT,
    const float* __restrict__ bx,
    const float* __restrict__ W1, const float* __restrict__ b1,
    const float* __restrict__ W2, const float* __restrict__ b2,
    float* __restrict__ out)
{
    __shared__ float pool[96 * LST + TN * GS];
    float* Ah = pool;
    float* Ac = Ah + 32 * LST;
    float* Bh = Ac + 32 * LST;
    float* Bc = Bh + 16 * LST;
    float* gs = Bc + 16 * LST;
    __shared__ float z_s[80];

    const int b   = blockIdx.x;
    const int tid = threadIdx.x;

    for (int idx = tid; idx < 32 * HH; idx += 384) {
        int p = idx / HH, j = idx - p * HH;
        size_t base = ((size_t)b * 32 + p) * HH + j;
        Ah[p * LST + j] = in_h[base];
        Ac[p * LST + j] = in_c[base];
    }

    const int o1 = tid, o2 = tid + 384;
    const float bx1 = bx[o1];
    const float bx2 = (o2 < 750) ? bx[o2] : 0.0f;
    const float* ul1 = ULT + o1; const float* ur1 = URT + o1;
    const float* ul2 = ULT + o2; const float* ur2 = URT + o2;

    float* curh = Ah; float* curc = Ac;
    float* nxth = Bh; float* nxtc = Bc;

    for (int n = 16; n >= 1; n >>= 1) {
        __syncthreads();
        {
            float a1[TN], a2[TN];
            #pragma unroll
            for (int m = 0; m < TN; ++m) { a1[m] = bx1; a2[m] = bx2; }
            for (int j = 0; j < 150; j += 2) {
                int r0 = j * UST, r1 = (j + 1) * UST;
                float wl1a = ul1[r0], wl1b = ul1[r1];
                float wr1a = ur1[r0], wr1b = ur1[r1];
                float wl2a = ul2[r0], wl2b = ul2[r1];
                float wr2a = ur2[r0], wr2b = ur2[r1];
                #pragma unroll
                for (int m = 0; m < TN; ++m) {
                    float2 lv = *(const float2*)(curh + (2 * m) * LST + j);
                    float2 rv = *(const float2*)(curh + (2 * m + 1) * LST + j);
                    a1[m] += lv.x * wl1a + lv.y * wl1b + rv.x * wr1a + rv.y * wr1b;
                    a2[m] += lv.x * wl2a + lv.y * wl2b + rv.x * wr2a + rv.y * wr2b;
                }
            }
            #pragma unroll
            for (int m = 0; m < TN; ++m) {
                if (m < n) {
                    gs[m * GS + o1] = a1[m];
                    if (o2 < 750) gs[m * GS + o2] = a2[m];
                }
            }
        }
        __syncthreads();
        for (int idx = tid; idx < n * HH; idx += 384) {
            int m = idx / HH, h = idx - m * HH;
            float iv = sigmoidf_(gs[m * GS + h]);
            float fL = sigmoidf_(gs[m * GS + 150 + h]);
            float fR = sigmoidf_(gs[m * GS + 300 + h]);
            float ov = sigmoidf_(gs[m * GS + 450 + h]);
            float uv = tanh_fast(gs[m * GS + 600 + h]);
            float cc = iv * uv + fL * curc[2 * m * LST + h] + fR * curc[(2 * m + 1) * LST + h];
            nxth[m * LST + h] = ov * tanh_fast(cc);
            nxtc[m * LST + h] = cc;
        }
        float* t;
        t = curh; curh = nxth; nxth = t;
        t = curc; curc = nxtc; nxtc = t;
    }
    __syncthreads();

    // head MLP on root (= curh row 0)
    if (tid < 75) {
        const float* w = W1 + (size_t)tid * 150;
        float acc = b1[tid];
        for (int j = 0; j < 150; ++j) acc += curh[j] * w[j];
        z_s[tid] = fmaxf(acc, 0.0f);
    }
    __syncthreads();
    if (tid < 3) {
        const float* w = W2 + (size_t)tid * 75;
        float acc = b2[tid];
        for (int j = 0; j < 75; ++j) acc += z_s[j] * w[j];
        out[(size_t)b * 3 + tid] = acc;
    }
}

extern "C" void kernel_launch(void* const* d_in, const int* in_sizes, int n_in,
                              void* d_out, int out_size, void* d_ws, size_t ws_size,
                              hipStream_t stream) {
    const int*   x   = (const int*)  d_in[0];
    const float* emb = (const float*)d_in[1];
    const float* w3  = (const float*)d_in[2];
    const float* b3  = (const float*)d_in[3];
    const float* w4  = (const float*)d_in[4];
    const float* b4  = (const float*)d_in[5];
    const float* w5  = (const float*)d_in[6];
    const float* b5  = (const float*)d_in[7];
    const float* Wp  = (const float*)d_in[8];
    const float* bp  = (const float*)d_in[9];
    const float* Wx  = (const float*)d_in[10];
    const float* bx  = (const float*)d_in[11];
    const float* UL  = (const float*)d_in[12];
    const float* UR  = (const float*)d_in[13];
    const float* W1  = (const float*)d_in[14];
    const float* b1  = (const float*)d_in[15];
    const float* W2  = (const float*)d_in[16];
    const float* b2  = (const float*)d_in[17];
    float* out = (float*)d_out;

    float* ws    = (float*)d_ws;
    float* w5u_T = ws + OFF_W5UT;
    float* bcat  = ws + OFF_BCAT;
    float* WpT   = ws + OFF_WPT;
    float* WxT   = ws + OFF_WXT;
    float* ULT   = ws + OFF_ULT;
    float* URT   = ws + OFF_URT;
    float* h0    = ws + OFF_H0;
    float* c0    = ws + OFF_C0;
    float* h1    = ws + OFF_H1;
    float* c1    = ws + OFF_C1;

    k_prep<<<(838200 + 255) / 256, 256, 0, stream>>>(
        w3, b3, w4, b4, w5, b5, Wp, Wx, UL, UR, ws);

    k_leaf<<<dim3(BB, SS / TP), 320, 0, stream>>>(
        x, emb, w5u_T, bcat, WpT, WxT, bp, bx, h0, c0);

    k_tree<<<dim3(BB, 16), 384, 0, stream>>>(h0, c0, h1, c1, 256, ULT, URT, bx);
    k_tree<<<dim3(BB,  8), 384, 0, stream>>>(h1, c1, h0, c0, 128, ULT, URT, bx);
    k_tree<<<dim3(BB,  4), 384, 0, stream>>>(h0, c0, h1, c1,  64, ULT, URT, bx);
    k_tree<<<dim3(BB,  2), 384, 0, stream>>>(h1, c1, h0, c0,  32, ULT, URT, bx);

    k_tail<<<BB, 384, 0, stream>>>(h0, c0, ULT, URT, bx, W1, b1, W2, b2, out);
}

// Round 4
// 1614.079 us; speedup vs baseline: 6.1947x; 1.8860x over previous
//
#include <hip/hip_runtime.h>
#include <math.h>

#define BB 128
#define SS 512
#define EE 300
#define HH 150
#define TN 16
#define LST 152  // tree LDS row stride (floats)
#define GS 752   // gate buffer row stride
#define UST 752  // transposed UL/UR row stride (cols 750..751 zero)

// ---- workspace byte offsets ----
#define OB_B1   0u            // conv B frags: 830 tiles * 2048 B
#define OB_B2   1699840u      // leaf-proj B frags: 200 tiles
#define OB_B3   2109440u      // leaf-gate B frags: 150 tiles
#define OB_BC   2416640u      // bcat: 304 floats
#define OB_ULT  2418176u      // 150*752 floats
#define OB_URT  2869376u
#define OB_H0   3320832u
#define SZB_HC0 39321600u     // 128*512*150*4
#define OB_C0   (OB_H0 + SZB_HC0)
#define OB_H1   (OB_C0 + SZB_HC0)
#define SZB_HC1 19660800u
#define OB_C1   (OB_H1 + SZB_HC1)

// LDS strides (ushorts)
#define EST 328
#define CST 328
#define LSU 168

typedef short s16x8 __attribute__((ext_vector_type(8)));
typedef float f32x4 __attribute__((ext_vector_type(4)));
#define MFMA __builtin_amdgcn_mfma_f32_16x16x32_bf16

typedef unsigned short ushort_t;
typedef unsigned int uint_t;

__device__ __forceinline__ float sigmoidf_(float x) {
    return 1.0f / (1.0f + __expf(-x));
}
__device__ __forceinline__ float tanh_fast(float x) {
    x = fminf(fmaxf(x, -15.0f), 15.0f);
    float e = __expf(2.0f * x);
    return (e - 1.0f) / (e + 1.0f);
}
// split fp32 -> bf16 hi + bf16 lo (RNE both)
__device__ __forceinline__ void split_bf16(float f, ushort_t& hi, ushort_t& lo) {
    uint_t u = __float_as_uint(f);
    uint_t r = (u + 0x7fffu + ((u >> 16) & 1u)) >> 16;
    hi = (ushort_t)r;
    float d = f - __uint_as_float(r << 16);
    uint_t u2 = __float_as_uint(d);
    uint_t r2 = (u2 + 0x7fffu + ((u2 >> 16) & 1u)) >> 16;
    lo = (ushort_t)r2;
}

// conv B1 tile index: nt<12 -> kts 10..49 (40), nt>=12 -> kts 0..49 (50)
__device__ __forceinline__ int b1_tile(int nt, int kt) {
    return (nt < 12) ? nt * 40 + (kt - 10) : 480 + (nt - 12) * 50 + kt;
}

// ---------------- k_prep: build split-bf16 fragment arrays + fp32 ULT/URT + bcat --------
// B-frag storage: per (tile, lane): 32 B = [8 bf16 hi][8 bf16 lo]
//   logical B[k][n], lane: n = tile_n*16 + (lane&15), k-run = tile_k*32 + (lane>>4)*8
__global__ __launch_bounds__(256) void k_prep(
    const float* __restrict__ w3, const float* __restrict__ b3,
    const float* __restrict__ w4, const float* __restrict__ b4,
    const float* __restrict__ w5, const float* __restrict__ b5,
    const float* __restrict__ Wp, const float* __restrict__ Wx,
    const float* __restrict__ UL, const float* __restrict__ UR,
    char* __restrict__ wsb)
{
    const int W1 = 830 * 64, W2 = 200 * 64, W3 = 150 * 64;
    int i = blockIdx.x * 256 + threadIdx.x;
    if (i < W1) {
        // conv: K = t*320+jj (t tap 0..4, jj 0..319), N = f (0..303)
        int T = i >> 6, lane = i & 63;
        int nt, kt;
        if (T < 480) { nt = T / 40; kt = T % 40 + 10; }
        else { int T2 = T - 480; nt = 12 + T2 / 50; kt = T2 % 50; }
        int t = kt / 10, jjb = (kt - t * 10) * 32 + ((lane >> 4) << 3);
        int f = nt * 16 + (lane & 15);
        ushort_t hv[8], lv[8];
        #pragma unroll
        for (int e = 0; e < 8; ++e) {
            int jj = jjb + e;
            float w = 0.0f;
            if (f < 300 && jj < 300) {
                if (f < 100)      { if (t >= 1 && t <= 3) w = w3[f * 900 + jj * 3 + (t - 1)]; }
                else if (f < 200) { if (t >= 1)           w = w4[(f - 100) * 1200 + jj * 4 + (t - 1)]; }
                else              {                       w = w5[(f - 200) * 1500 + jj * 5 + t]; }
            }
            split_bf16(w, hv[e], lv[e]);
        }
        uint_t* out = (uint_t*)(wsb + OB_B1 + ((size_t)T * 64 + lane) * 32);
        out[0] = hv[0] | (hv[1] << 16); out[1] = hv[2] | (hv[3] << 16);
        out[2] = hv[4] | (hv[5] << 16); out[3] = hv[6] | (hv[7] << 16);
        out[4] = lv[0] | (lv[1] << 16); out[5] = lv[2] | (lv[3] << 16);
        out[6] = lv[4] | (lv[5] << 16); out[7] = lv[6] | (lv[7] << 16);
        return;
    }
    i -= W1;
    if (i < W2) {
        // leaf proj: K: [0,320) = e cols (valid<300), [320,640) = cnn cols (valid<300); N = h
        int T = i >> 6, lane = i & 63;
        int nt = T / 20, kt = T % 20;
        int h = nt * 16 + (lane & 15);
        int kb = kt * 32 + ((lane >> 4) << 3);
        ushort_t hv[8], lv[8];
        #pragma unroll
        for (int e = 0; e < 8; ++e) {
            int k = kb + e;
            float w = 0.0f;
            if (h < 150) {
                if (kt < 10) { if (k < 300) w = Wp[h * 600 + k]; }
                else { int k2 = k - 320; if (k2 < 300) w = Wp[h * 600 + 300 + k2]; }
            }
            split_bf16(w, hv[e], lv[e]);
        }
        uint_t* out = (uint_t*)(wsb + OB_B2 + ((size_t)T * 64 + lane) * 32);
        out[0] = hv[0] | (hv[1] << 16); out[1] = hv[2] | (hv[3] << 16);
        out[2] = hv[4] | (hv[5] << 16); out[3] = hv[6] | (hv[7] << 16);
        out[4] = lv[0] | (lv[1] << 16); out[5] = lv[2] | (lv[3] << 16);
        out[6] = lv[4] | (lv[5] << 16); out[7] = lv[6] | (lv[7] << 16);
        return;
    }
    i -= W2;
    if (i < W3) {
        // leaf gates: K = leaf (valid<150), N = g*160+h, g in {i,o,u} -> Wx rows {0,450,600}+h
        int T = i >> 6, lane = i & 63;
        int nt3 = T / 5, kt = T % 5;
        int g = nt3 / 10, h16 = nt3 % 10;
        int h = h16 * 16 + (lane & 15);
        int kb = kt * 32 + ((lane >> 4) << 3);
        int row = (g == 0 ? 0 : (g == 1 ? 450 : 600)) + h;
        ushort_t hv[8], lv[8];
        #pragma unroll
        for (int e = 0; e < 8; ++e) {
            int k = kb + e;
            float w = (h < 150 && k < 150) ? Wx[row * 150 + k] : 0.0f;
            split_bf16(w, hv[e], lv[e]);
        }
        uint_t* out = (uint_t*)(wsb + OB_B3 + ((size_t)T * 64 + lane) * 32);
        out[0] = hv[0] | (hv[1] << 16); out[1] = hv[2] | (hv[3] << 16);
        out[2] = hv[4] | (hv[5] << 16); out[3] = hv[6] | (hv[7] << 16);
        out[4] = lv[0] | (lv[1] << 16); out[5] = lv[2] | (lv[3] << 16);
        out[6] = lv[4] | (lv[7 - 7 + 7] << 16); // lv[7]? fixed below
        out[6] = lv[4] | (lv[5] << 16); out[7] = lv[6] | (lv[7] << 16);
        return;
    }
    i -= W3;
    if (i < 304) {
        float v = (i < 100) ? b3[i] : (i < 200 ? b4[i - 100] : (i < 300 ? b5[i - 200] : 0.0f));
        ((float*)(wsb + OB_BC))[i] = v;
        return;
    }
    i -= 304;
    if (i < 150 * UST) {
        int j = i / UST, o = i - j * UST;
        ((float*)(wsb + OB_ULT))[i] = (o < 750) ? UL[o * 150 + j] : 0.0f;
        return;
    }
    i -= 150 * UST;
    if (i < 150 * UST) {
        int j = i / UST, o = i - j * UST;
        ((float*)(wsb + OB_URT))[i] = (o < 750) ? UR[o * 150 + j] : 0.0f;
        return;
    }
}

// ---------------- k_leaf: MFMA split-bf16, 32 positions/block, 640 threads (10 waves) ----
// phase1 conv: C[32][304] = A_im2col[32][1600] x B1 ; phase2 leaf = [e|cnn] x B2 ;
// phase3 gates(i,o,u) = leaf x B3 ; cell -> h0,c0 (fp32)
__global__ __launch_bounds__(640) void k_leaf(
    const int* __restrict__ x, const float* __restrict__ emb,
    const ushort_t* __restrict__ b1f, const ushort_t* __restrict__ b2f,
    const ushort_t* __restrict__ b3f, const float* __restrict__ bcat,
    const float* __restrict__ bp, const float* __restrict__ bx,
    float* __restrict__ h0, float* __restrict__ c0)
{
    __shared__ ushort_t ehi[36 * EST], elo[36 * EST];
    __shared__ ushort_t chi[32 * CST], clo[32 * CST];
    __shared__ ushort_t lhi[32 * LSU], llo[32 * LSU];

    const int b   = blockIdx.x;
    const int s0  = blockIdx.y * 32;
    const int tid = threadIdx.x;
    const int wv  = tid >> 6;
    const int lane = tid & 63;
    const int lc = lane & 15, lq = lane >> 4;

    // ---- phase 0: gather e rows (36 x 300), split to bf16 hi/lo ----
    for (int idx = tid; idx < 36 * 75; idx += 640) {
        int r = idx / 75, q = idx - r * 75;
        int sp = s0 - 2 + r;
        float4 v = make_float4(0.f, 0.f, 0.f, 0.f);
        if (sp >= 0 && sp < SS) {
            int tok = x[b * SS + sp];
            v = *reinterpret_cast<const float4*>(emb + (size_t)tok * EE + q * 4);
        }
        ushort_t h4[4], l4[4];
        split_bf16(v.x, h4[0], l4[0]); split_bf16(v.y, h4[1], l4[1]);
        split_bf16(v.z, h4[2], l4[2]); split_bf16(v.w, h4[3], l4[3]);
        *(ushort4*)&ehi[r * EST + q * 4] = make_ushort4(h4[0], h4[1], h4[2], h4[3]);
        *(ushort4*)&elo[r * EST + q * 4] = make_ushort4(l4[0], l4[1], l4[2], l4[3]);
    }
    // zero pads: e cols 300..319, cnn cols 304..319 (avoid NaN garbage into MFMA)
    for (int idx = tid; idx < 36 * 20; idx += 640) {
        int r = idx / 20, c = 300 + idx % 20;
        ehi[r * EST + c] = 0; elo[r * EST + c] = 0;
    }
    for (int idx = tid; idx < 32 * 16; idx += 640) {
        int r = idx / 16, c = 304 + idx % 16;
        chi[r * CST + c] = 0; clo[r * CST + c] = 0;
    }
    __syncthreads();

    // ---- phase 1: conv GEMM ----
    {
        const bool has1 = (wv < 9);
        const int nt0 = wv, nt1 = wv + 10;
        const int kt01 = (nt1 < 12) ? 10 : 0;
        const int f0 = nt0 * 16 + lc;
        const int f1 = nt1 * 16 + lc;
        const float bv0 = bcat[f0];
        const float bv1 = (has1 && f1 < 300) ? bcat[f1] : 0.0f;
        f32x4 c00 = {bv0, bv0, bv0, bv0}, c01 = c00;
        f32x4 c10 = {bv1, bv1, bv1, bv1}, c11 = c10;
        const int ktstart = has1 ? (kt01 < 10 ? 0 : 10) : 10;
        for (int kt = ktstart; kt < 50; ++kt) {
            int t = kt / 10;
            int jj = (kt - t * 10) * 32 + (lq << 3);
            int ra = lc + t;
            s16x8 A0h = *(const s16x8*)&ehi[ra * EST + jj];
            s16x8 A0l = *(const s16x8*)&elo[ra * EST + jj];
            s16x8 A1h = *(const s16x8*)&ehi[(ra + 16) * EST + jj];
            s16x8 A1l = *(const s16x8*)&elo[(ra + 16) * EST + jj];
            if (kt >= 10) {
                const ushort_t* p8 = b1f + ((size_t)b1_tile(nt0, kt) * 64 + lane) * 16;
                s16x8 Bh = *(const s16x8*)p8;
                s16x8 Bl = *(const s16x8*)(p8 + 8);
                c00 = MFMA(A0h, Bh, c00, 0, 0, 0);
                c00 = MFMA(A0h, Bl, c00, 0, 0, 0);
                c00 = MFMA(A0l, Bh, c00, 0, 0, 0);
                c01 = MFMA(A1h, Bh, c01, 0, 0, 0);
                c01 = MFMA(A1h, Bl, c01, 0, 0, 0);
                c01 = MFMA(A1l, Bh, c01, 0, 0, 0);
            }
            if (has1 && kt >= kt01) {
                const ushort_t* p8 = b1f + ((size_t)b1_tile(nt1, kt) * 64 + lane) * 16;
                s16x8 Bh = *(const s16x8*)p8;
                s16x8 Bl = *(const s16x8*)(p8 + 8);
                c10 = MFMA(A0h, Bh, c10, 0, 0, 0);
                c10 = MFMA(A0h, Bl, c10, 0, 0, 0);
                c10 = MFMA(A0l, Bh, c10, 0, 0, 0);
                c11 = MFMA(A1h, Bh, c11, 0, 0, 0);
                c11 = MFMA(A1h, Bl, c11, 0, 0, 0);
                c11 = MFMA(A1l, Bh, c11, 0, 0, 0);
            }
        }
        #pragma unroll
        for (int r = 0; r < 4; ++r) {
            int p = lq * 4 + r;
            ushort_t hu, lu;
            split_bf16(fmaxf(c00[r], 0.0f), hu, lu);
            chi[p * CST + f0] = hu; clo[p * CST + f0] = lu;
            split_bf16(fmaxf(c01[r], 0.0f), hu, lu);
            chi[(p + 16) * CST + f0] = hu; clo[(p + 16) * CST + f0] = lu;
            if (has1) {
                split_bf16(fmaxf(c10[r], 0.0f), hu, lu);
                chi[p * CST + f1] = hu; clo[p * CST + f1] = lu;
                split_bf16(fmaxf(c11[r], 0.0f), hu, lu);
                chi[(p + 16) * CST + f1] = hu; clo[(p + 16) * CST + f1] = lu;
            }
        }
    }
    __syncthreads();

    // ---- phase 2: leaf projection GEMM ----
    {
        const int hcol = wv * 16 + lc;   // < 160
        const float bv = (hcol < 150) ? bp[hcol] : 0.0f;
        f32x4 d0 = {bv, bv, bv, bv}, d1 = d0;
        for (int kt = 0; kt < 20; ++kt) {
            s16x8 A0h, A0l, A1h, A1l;
            if (kt < 10) {
                int col = kt * 32 + (lq << 3);
                int ra = lc + 2;
                A0h = *(const s16x8*)&ehi[ra * EST + col];
                A0l = *(const s16x8*)&elo[ra * EST + col];
                A1h = *(const s16x8*)&ehi[(ra + 16) * EST + col];
                A1l = *(const s16x8*)&elo[(ra + 16) * EST + col];
            } else {
                int col = (kt - 10) * 32 + (lq << 3);
                A0h = *(const s16x8*)&chi[lc * CST + col];
                A0l = *(const s16x8*)&clo[lc * CST + col];
                A1h = *(const s16x8*)&chi[(lc + 16) * CST + col];
                A1l = *(const s16x8*)&clo[(lc + 16) * CST + col];
            }
            const ushort_t* p8 = b2f + ((size_t)(wv * 20 + kt) * 64 + lane) * 16;
            s16x8 Bh = *(const s16x8*)p8;
            s16x8 Bl = *(const s16x8*)(p8 + 8);
            d0 = MFMA(A0h, Bh, d0, 0, 0, 0);
            d0 = MFMA(A0h, Bl, d0, 0, 0, 0);
            d0 = MFMA(A0l, Bh, d0, 0, 0, 0);
            d1 = MFMA(A1h, Bh, d1, 0, 0, 0);
            d1 = MFMA(A1h, Bl, d1, 0, 0, 0);
            d1 = MFMA(A1l, Bh, d1, 0, 0, 0);
        }
        #pragma unroll
        for (int r = 0; r < 4; ++r) {
            int p = lq * 4 + r;
            ushort_t hu, lu;
            split_bf16(d0[r], hu, lu);
            lhi[p * LSU + hcol] = hu; llo[p * LSU + hcol] = lu;
            split_bf16(d1[r], hu, lu);
            lhi[(p + 16) * LSU + hcol] = hu; llo[(p + 16) * LSU + hcol] = lu;
        }
    }
    __syncthreads();

    // ---- phase 3: leaf gates (i,o,u) GEMM + cell ----
    {
        const int hc = wv * 16 + lc;
        const bool hval = (hc < 150);
        const float bi = hval ? bx[hc] : 0.0f;
        const float bo = hval ? bx[450 + hc] : 0.0f;
        const float bu = hval ? bx[600 + hc] : 0.0f;
        f32x4 gi0 = {bi, bi, bi, bi}, gi1 = gi0;
        f32x4 go0 = {bo, bo, bo, bo}, go1 = go0;
        f32x4 gu0 = {bu, bu, bu, bu}, gu1 = gu0;
        for (int kt = 0; kt < 5; ++kt) {
            int col = kt * 32 + (lq << 3);
            s16x8 A0h = *(const s16x8*)&lhi[lc * LSU + col];
            s16x8 A0l = *(const s16x8*)&llo[lc * LSU + col];
            s16x8 A1h = *(const s16x8*)&lhi[(lc + 16) * LSU + col];
            s16x8 A1l = *(const s16x8*)&llo[(lc + 16) * LSU + col];
            const ushort_t* p8i = b3f + ((size_t)((0 + wv) * 5 + kt) * 64 + lane) * 16;
            const ushort_t* p8o = b3f + ((size_t)((10 + wv) * 5 + kt) * 64 + lane) * 16;
            const ushort_t* p8u = b3f + ((size_t)((20 + wv) * 5 + kt) * 64 + lane) * 16;
            s16x8 Bh, Bl;
            Bh = *(const s16x8*)p8i; Bl = *(const s16x8*)(p8i + 8);
            gi0 = MFMA(A0h, Bh, gi0, 0, 0, 0); gi0 = MFMA(A0h, Bl, gi0, 0, 0, 0); gi0 = MFMA(A0l, Bh, gi0, 0, 0, 0);
            gi1 = MFMA(A1h, Bh, gi1, 0, 0, 0); gi1 = MFMA(A1h, Bl, gi1, 0, 0, 0); gi1 = MFMA(A1l, Bh, gi1, 0, 0, 0);
            Bh = *(const s16x8*)p8o; Bl = *(const s16x8*)(p8o + 8);
            go0 = MFMA(A0h, Bh, go0, 0, 0, 0); go0 = MFMA(A0h, Bl, go0, 0, 0, 0); go0 = MFMA(A0l, Bh, go0, 0, 0, 0);
            go1 = MFMA(A1h, Bh, go1, 0, 0, 0); go1 = MFMA(A1h, Bl, go1, 0, 0, 0); go1 = MFMA(A1l, Bh, go1, 0, 0, 0);
            Bh = *(const s16x8*)p8u; Bl = *(const s16x8*)(p8u + 8);
            gu0 = MFMA(A0h, Bh, gu0, 0, 0, 0); gu0 = MFMA(A0h, Bl, gu0, 0, 0, 0); gu0 = MFMA(A0l, Bh, gu0, 0, 0, 0);
            gu1 = MFMA(A1h, Bh, gu1, 0, 0, 0); gu1 = MFMA(A1h, Bl, gu1, 0, 0, 0); gu1 = MFMA(A1l, Bh, gu1, 0, 0, 0);
        }
        if (hval) {
            #pragma unroll
            for (int r = 0; r < 4; ++r) {
                {
                    int s = s0 + lq * 4 + r;
                    float iv = sigmoidf_(gi0[r]), ov = sigmoidf_(go0[r]), uv = tanh_fast(gu0[r]);
                    float cc = iv * uv;
                    size_t o = ((size_t)b * SS + s) * HH + hc;
                    h0[o] = ov * tanh_fast(cc);
                    c0[o] = cc;
                }
                {
                    int s = s0 + 16 + lq * 4 + r;
                    float iv = sigmoidf_(gi1[r]), ov = sigmoidf_(go1[r]), uv = tanh_fast(gu1[r]);
                    float cc = iv * uv;
                    size_t o = ((size_t)b * SS + s) * HH + hc;
                    h0[o] = ov * tanh_fast(cc);
                    c0[o] = cc;
                }
            }
        }
    }
}

// ---------------- k_tree: unchanged proven fp32 path (UST=752 + clamped o2 reads) -------
__global__ __launch_bounds__(384) void k_tree(
    const float* __restrict__ in_h, const float* __restrict__ in_c,
    float* __restrict__ out_h, float* __restrict__ out_c,
    int n_out,
    const float* __restrict__ ULT, const float* __restrict__ URT,
    const float* __restrict__ bx)
{
    __shared__ float lh_s[TN][LST], rh_s[TN][LST];
    __shared__ float g_s[TN][GS];

    const int b    = blockIdx.x;
    const int m0   = blockIdx.y * TN;
    const int tid  = threadIdx.x;
    const int n_in = n_out * 2;

    for (int idx = tid; idx < TN * HH; idx += 384) {
        int p = idx / HH, j = idx - p * HH;
        size_t base = ((size_t)b * n_in + 2 * (m0 + p)) * HH + j;
        lh_s[p][j] = in_h[base];
        rh_s[p][j] = in_h[base + HH];
    }
    __syncthreads();

    {
        const int o1 = tid, o2 = tid + 384;
        const int o2c = (o2 < 752) ? o2 : 751;
        float a1[TN], a2[TN];
        float b1v = bx[o1];
        float b2v = (o2 < 750) ? bx[o2] : 0.0f;
        #pragma unroll
        for (int m = 0; m < TN; ++m) { a1[m] = b1v; a2[m] = b2v; }
        const float* ul1 = ULT + o1; const float* ur1 = URT + o1;
        const float* ul2 = ULT + o2c; const float* ur2 = URT + o2c;
        for (int j = 0; j < 150; j += 2) {
            int r0 = j * UST, r1 = (j + 1) * UST;
            float wl1a = ul1[r0], wl1b = ul1[r1];
            float wr1a = ur1[r0], wr1b = ur1[r1];
            float wl2a = ul2[r0], wl2b = ul2[r1];
            float wr2a = ur2[r0], wr2b = ur2[r1];
            #pragma unroll
            for (int m = 0; m < TN; ++m) {
                float2 lv = *(const float2*)(&lh_s[m][j]);
                float2 rv = *(const float2*)(&rh_s[m][j]);
                a1[m] += lv.x * wl1a + lv.y * wl1b + rv.x * wr1a + rv.y * wr1b;
                a2[m] += lv.x * wl2a + lv.y * wl2b + rv.x * wr2a + rv.y * wr2b;
            }
        }
        #pragma unroll
        for (int m = 0; m < TN; ++m) {
            g_s[m][o1] = a1[m];
            if (o2 < 750) g_s[m][o2] = a2[m];
        }
    }
    __syncthreads();

    for (int idx = tid; idx < TN * HH; idx += 384) {
        int m = idx / HH, h = idx - m * HH;
        float iv = sigmoidf_(g_s[m][h]);
        float fL = sigmoidf_(g_s[m][150 + h]);
        float fR = sigmoidf_(g_s[m][300 + h]);
        float ov = sigmoidf_(g_s[m][450 + h]);
        float uv = tanh_fast(g_s[m][600 + h]);
        size_t lbase = ((size_t)b * n_in + 2 * (m0 + m)) * HH + h;
        float cc = iv * uv + fL * in_c[lbase] + fR * in_c[lbase + HH];
        size_t obase = ((size_t)b * n_out + m0 + m) * HH + h;
        out_h[obase] = ov * tanh_fast(cc);
        out_c[obase] = cc;
    }
}

// ---------------- k_tail: levels 16..1 in LDS + head MLP (unchanged, UST/clamp) ---------
__global__ __launch_bounds__(384) void k_tail(
    const float* __restrict__ in_h, const float* __restrict__ in_c,
    const float* __restrict__ ULT, const float* __restrict__ URT,
    const float* __restrict__ bx,
    const float* __restrict__ W1, const float* __restrict__ b1,
    const float* __restrict__ W2, const float* __restrict__ b2,
    float* __restrict__ out)
{
    __shared__ float pool[96 * LST + TN * GS];
    float* Ah = pool;
    float* Ac = Ah + 32 * LST;
    float* Bh = Ac + 32 * LST;
    float* Bc = Bh + 16 * LST;
    float* gs = Bc + 16 * LST;
    __shared__ float z_s[80];

    const int b   = blockIdx.x;
    const int tid = threadIdx.x;

    for (int idx = tid; idx < 32 * HH; idx += 384) {
        int p = idx / HH, j = idx - p * HH;
        size_t base = ((size_t)b * 32 + p) * HH + j;
        Ah[p * LST + j] = in_h[base];
        Ac[p * LST + j] = in_c[base];
    }

    const int o1 = tid, o2 = tid + 384;
    const int o2c = (o2 < 752) ? o2 : 751;
    const float bx1 = bx[o1];
    const float bx2 = (o2 < 750) ? bx[o2] : 0.0f;
    const float* ul1 = ULT + o1; const float* ur1 = URT + o1;
    const float* ul2 = ULT + o2c; const float* ur2 = URT + o2c;

    float* curh = Ah; float* curc = Ac;
    float* nxth = Bh; float* nxtc = Bc;

    for (int n = 16; n >= 1; n >>= 1) {
        __syncthreads();
        {
            float a1[TN], a2[TN];
            #pragma unroll
            for (int m = 0; m < TN; ++m) { a1[m] = bx1; a2[m] = bx2; }
            for (int j = 0; j < 150; j += 2) {
                int r0 = j * UST, r1 = (j + 1) * UST;
                float wl1a = ul1[r0], wl1b = ul1[r1];
                float wr1a = ur1[r0], wr1b = ur1[r1];
                float wl2a = ul2[r0], wl2b = ul2[r1];
                float wr2a = ur2[r0], wr2b = ur2[r1];
                #pragma unroll
                for (int m = 0; m < TN; ++m) {
                    float2 lv = *(const float2*)(curh + (2 * m) * LST + j);
                    float2 rv = *(const float2*)(curh + (2 * m + 1) * LST + j);
                    a1[m] += lv.x * wl1a + lv.y * wl1b + rv.x * wr1a + rv.y * wr1b;
                    a2[m] += lv.x * wl2a + lv.y * wl2b + rv.x * wr2a + rv.y * wr2b;
                }
            }
            #pragma unroll
            for (int m = 0; m < TN; ++m) {
                if (m < n) {
                    gs[m * GS + o1] = a1[m];
                    if (o2 < 750) gs[m * GS + o2] = a2[m];
                }
            }
        }
        __syncthreads();
        for (int idx = tid; idx < n * HH; idx += 384) {
            int m = idx / HH, h = idx - m * HH;
            float iv = sigmoidf_(gs[m * GS + h]);
            float fL = sigmoidf_(gs[m * GS + 150 + h]);
            float fR = sigmoidf_(gs[m * GS + 300 + h]);
            float ov = sigmoidf_(gs[m * GS + 450 + h]);
            float uv = tanh_fast(gs[m * GS + 600 + h]);
            float cc = iv * uv + fL * curc[2 * m * LST + h] + fR * curc[(2 * m + 1) * LST + h];
            nxth[m * LST + h] = ov * tanh_fast(cc);
            nxtc[m * LST + h] = cc;
        }
        float* t;
        t = curh; curh = nxth; nxth = t;
        t = curc; curc = nxtc; nxtc = t;
    }
    __syncthreads();

    if (tid < 75) {
        const float* w = W1 + (size_t)tid * 150;
        float acc = b1[tid];
        for (int j = 0; j < 150; ++j) acc += curh[j] * w[j];
        z_s[tid] = fmaxf(acc, 0.0f);
    }
    __syncthreads();
    if (tid < 3) {
        const float* w = W2 + (size_t)tid * 75;
        float acc = b2[tid];
        for (int j = 0; j < 75; ++j) acc += z_s[j] * w[j];
        out[(size_t)b * 3 + tid] = acc;
    }
}

extern "C" void kernel_launch(void* const* d_in, const int* in_sizes, int n_in,
                              void* d_out, int out_size, void* d_ws, size_t ws_size,
                              hipStream_t stream) {
    const int*   x   = (const int*)  d_in[0];
    const float* emb = (const float*)d_in[1];
    const float* w3  = (const float*)d_in[2];
    const float* b3  = (const float*)d_in[3];
    const float* w4  = (const float*)d_in[4];
    const float* b4  = (const float*)d_in[5];
    const float* w5  = (const float*)d_in[6];
    const float* b5  = (const float*)d_in[7];
    const float* Wp  = (const float*)d_in[8];
    const float* bp  = (const float*)d_in[9];
    const float* Wx  = (const float*)d_in[10];
    const float* bx  = (const float*)d_in[11];
    const float* UL  = (const float*)d_in[12];
    const float* UR  = (const float*)d_in[13];
    const float* W1  = (const float*)d_in[14];
    const float* b1  = (const float*)d_in[15];
    const float* W2  = (const float*)d_in[16];
    const float* b2  = (const float*)d_in[17];
    float* out = (float*)d_out;

    char* wsb = (char*)d_ws;
    const ushort_t* b1f = (const ushort_t*)(wsb + OB_B1);
    const ushort_t* b2f = (const ushort_t*)(wsb + OB_B2);
    const ushort_t* b3f = (const ushort_t*)(wsb + OB_B3);
    const float* bcat = (const float*)(wsb + OB_BC);
    const float* ULT  = (const float*)(wsb + OB_ULT);
    const float* URT  = (const float*)(wsb + OB_URT);
    float* h0 = (float*)(wsb + OB_H0);
    float* c0 = (float*)(wsb + OB_C0);
    float* h1 = (float*)(wsb + OB_H1);
    float* c1 = (float*)(wsb + OB_C1);

    {
        int total = 830 * 64 + 200 * 64 + 150 * 64 + 304 + 2 * 150 * UST;
        k_prep<<<(total + 255) / 256, 256, 0, stream>>>(
            w3, b3, w4, b4, w5, b5, Wp, Wx, UL, UR, wsb);
    }

    k_leaf<<<dim3(BB, SS / 32), 640, 0, stream>>>(
        x, emb, b1f, b2f, b3f, bcat, bp, bx, h0, c0);

    k_tree<<<dim3(BB, 16), 384, 0, stream>>>(h0, c0, h1, c1, 256, ULT, URT, bx);
    k_tree<<<dim3(BB,  8), 384, 0, stream>>>(h1, c1, h0, c0, 128, ULT, URT, bx);
    k_tree<<<dim3(BB,  4), 384, 0, stream>>>(h0, c0, h1, c1,  64, ULT, URT, bx);
    k_tree<<<dim3(BB,  2), 384, 0, stream>>>(h1, c1, h0, c0,  32, ULT, URT, bx);

    k_tail<<<BB, 384, 0, stream>>>(h0, c0, ULT, URT, bx, W1, b1, W2, b2, out);
}

// Round 5
// 828.126 us; speedup vs baseline: 12.0739x; 1.9491x over previous
//
#include <hip/hip_runtime.h>
#include <math.h>

#define BB 128
#define SS 512
#define EE 300
#define HH 150
#define TN 16
#define LST 152  // tail LDS row stride (floats)
#define GS 752   // tail gate buffer row stride
#define UST 752  // transposed UL/UR row stride (cols 750..751 zero)

// ---- workspace byte offsets ----
#define OB_B1   0u            // conv B frags: 830 tiles * 2048 B
#define OB_B2   1699840u      // leaf-proj B frags: 200 tiles
#define OB_B3   2109440u      // leaf-gate B frags: 150 tiles
#define OB_UT   2416640u      // tree U frags: 500 tiles * 2048 B
#define OB_BC   3440640u      // bcat: 304 floats
#define OB_ULT  3442176u      // 150*752 floats (fp32, for k_tail)
#define OB_URT  3893376u
#define OB_H0   4344576u
#define SZB_HC0 39321600u     // 128*512*150*4
#define OB_C0   (OB_H0 + SZB_HC0)
#define OB_H1   (OB_C0 + SZB_HC0)
#define SZB_HC1 19660800u
#define OB_C1   (OB_H1 + SZB_HC1)

// LDS strides (ushorts)
#define EST 328
#define CST 328
#define LSU 168
#define AST 332  // tree A stride: bank-spread (332*2/4 = 166 ≡ 6 mod 32)

typedef short s16x8 __attribute__((ext_vector_type(8)));
typedef float f32x4 __attribute__((ext_vector_type(4)));
#define MFMA __builtin_amdgcn_mfma_f32_16x16x32_bf16

typedef unsigned short ushort_t;
typedef unsigned int uint_t;

__device__ __forceinline__ float sigmoidf_(float x) {
    return 1.0f / (1.0f + __expf(-x));
}
__device__ __forceinline__ float tanh_fast(float x) {
    x = fminf(fmaxf(x, -15.0f), 15.0f);
    float e = __expf(2.0f * x);
    return (e - 1.0f) / (e + 1.0f);
}
// split fp32 -> bf16 hi + bf16 lo (RNE both)
__device__ __forceinline__ void split_bf16(float f, ushort_t& hi, ushort_t& lo) {
    uint_t u = __float_as_uint(f);
    uint_t r = (u + 0x7fffu + ((u >> 16) & 1u)) >> 16;
    hi = (ushort_t)r;
    float d = f - __uint_as_float(r << 16);
    uint_t u2 = __float_as_uint(d);
    uint_t r2 = (u2 + 0x7fffu + ((u2 >> 16) & 1u)) >> 16;
    lo = (ushort_t)r2;
}

// conv B1 tile index: nt<12 -> kts 10..49 (40), nt>=12 -> kts 0..49 (50)
__device__ __forceinline__ int b1_tile(int nt, int kt) {
    return (nt < 12) ? nt * 40 + (kt - 10) : 480 + (nt - 12) * 50 + kt;
}

__device__ __forceinline__ void pack_frag(uint_t* out, const ushort_t* hv, const ushort_t* lv) {
    out[0] = hv[0] | (hv[1] << 16); out[1] = hv[2] | (hv[3] << 16);
    out[2] = hv[4] | (hv[5] << 16); out[3] = hv[6] | (hv[7] << 16);
    out[4] = lv[0] | (lv[1] << 16); out[5] = lv[2] | (lv[3] << 16);
    out[6] = lv[4] | (lv[5] << 16); out[7] = lv[6] | (lv[7] << 16);
}

// ---------------- k_prep: build split-bf16 fragment arrays + fp32 ULT/URT + bcat --------
// B-frag storage: per (tile, lane): 32 B = [8 bf16 hi][8 bf16 lo]
//   logical B[k][n], lane: n = tile_n*16 + (lane&15), k-run = tile_k*32 + (lane>>4)*8
__global__ __launch_bounds__(256) void k_prep(
    const float* __restrict__ w3, const float* __restrict__ b3,
    const float* __restrict__ w4, const float* __restrict__ b4,
    const float* __restrict__ w5, const float* __restrict__ b5,
    const float* __restrict__ Wp, const float* __restrict__ Wx,
    const float* __restrict__ UL, const float* __restrict__ UR,
    char* __restrict__ wsb)
{
    const int W1 = 830 * 64, W2 = 200 * 64, W3 = 150 * 64, WU = 500 * 64;
    int i = blockIdx.x * 256 + threadIdx.x;
    if (i < W1) {
        // conv: K = t*320+jj (t tap 0..4, jj 0..319), N = f (0..303)
        int T = i >> 6, lane = i & 63;
        int nt, kt;
        if (T < 480) { nt = T / 40; kt = T % 40 + 10; }
        else { int T2 = T - 480; nt = 12 + T2 / 50; kt = T2 % 50; }
        int t = kt / 10, jjb = (kt - t * 10) * 32 + ((lane >> 4) << 3);
        int f = nt * 16 + (lane & 15);
        ushort_t hv[8], lv[8];
        #pragma unroll
        for (int e = 0; e < 8; ++e) {
            int jj = jjb + e;
            float w = 0.0f;
            if (f < 300 && jj < 300) {
                if (f < 100)      { if (t >= 1 && t <= 3) w = w3[f * 900 + jj * 3 + (t - 1)]; }
                else if (f < 200) { if (t >= 1)           w = w4[(f - 100) * 1200 + jj * 4 + (t - 1)]; }
                else              {                       w = w5[(f - 200) * 1500 + jj * 5 + t]; }
            }
            split_bf16(w, hv[e], lv[e]);
        }
        pack_frag((uint_t*)(wsb + OB_B1 + ((size_t)T * 64 + lane) * 32), hv, lv);
        return;
    }
    i -= W1;
    if (i < W2) {
        // leaf proj: K: [0,320) = e cols (valid<300), [320,640) = cnn cols; N = h
        int T = i >> 6, lane = i & 63;
        int nt = T / 20, kt = T % 20;
        int h = nt * 16 + (lane & 15);
        int kb = kt * 32 + ((lane >> 4) << 3);
        ushort_t hv[8], lv[8];
        #pragma unroll
        for (int e = 0; e < 8; ++e) {
            int k = kb + e;
            float w = 0.0f;
            if (h < 150) {
                if (kt < 10) { if (k < 300) w = Wp[h * 600 + k]; }
                else { int k2 = k - 320; if (k2 < 300) w = Wp[h * 600 + 300 + k2]; }
            }
            split_bf16(w, hv[e], lv[e]);
        }
        pack_frag((uint_t*)(wsb + OB_B2 + ((size_t)T * 64 + lane) * 32), hv, lv);
        return;
    }
    i -= W2;
    if (i < W3) {
        // leaf gates: K = leaf (valid<150), N = g*160+h, g in {i,o,u} -> Wx rows {0,450,600}+h
        int T = i >> 6, lane = i & 63;
        int nt3 = T / 5, kt = T % 5;
        int g = nt3 / 10, h16 = nt3 % 10;
        int h = h16 * 16 + (lane & 15);
        int kb = kt * 32 + ((lane >> 4) << 3);
        int row = (g == 0 ? 0 : (g == 1 ? 450 : 600)) + h;
        ushort_t hv[8], lv[8];
        #pragma unroll
        for (int e = 0; e < 8; ++e) {
            int k = kb + e;
            float w = (h < 150 && k < 150) ? Wx[row * 150 + k] : 0.0f;
            split_bf16(w, hv[e], lv[e]);
        }
        pack_frag((uint_t*)(wsb + OB_B3 + ((size_t)T * 64 + lane) * 32), hv, lv);
        return;
    }
    i -= W3;
    if (i < WU) {
        // tree gates: tile T = (g*10 + ht)*10 + kt; K: [0,160)=lh cols, [160,320)=rh cols
        // N = h within h-tile; U row = g*150 + h; all 5 gates i,fL,fR,o,u
        int T = i >> 6, lane = i & 63;
        int g = T / 100, rem = T - g * 100;
        int ht = rem / 10, kt = rem - ht * 10;
        int h = ht * 16 + (lane & 15);
        int kb = kt * 32 + ((lane >> 4) << 3);
        ushort_t hv[8], lv[8];
        #pragma unroll
        for (int e = 0; e < 8; ++e) {
            int k = kb + e;
            int half = (k >= 160);
            int j = k - half * 160;
            float w = 0.0f;
            if (h < 150 && j < 150) {
                const float* U = half ? UR : UL;
                w = U[(g * 150 + h) * 150 + j];
            }
            split_bf16(w, hv[e], lv[e]);
        }
        pack_frag((uint_t*)(wsb + OB_UT + ((size_t)T * 64 + lane) * 32), hv, lv);
        return;
    }
    i -= WU;
    if (i < 304) {
        float v = (i < 100) ? b3[i] : (i < 200 ? b4[i - 100] : (i < 300 ? b5[i - 200] : 0.0f));
        ((float*)(wsb + OB_BC))[i] = v;
        return;
    }
    i -= 304;
    if (i < 150 * UST) {
        int j = i / UST, o = i - j * UST;
        ((float*)(wsb + OB_ULT))[i] = (o < 750) ? UL[o * 150 + j] : 0.0f;
        return;
    }
    i -= 150 * UST;
    if (i < 150 * UST) {
        int j = i / UST, o = i - j * UST;
        ((float*)(wsb + OB_URT))[i] = (o < 750) ? UR[o * 150 + j] : 0.0f;
        return;
    }
}

// ---------------- k_leaf: MFMA split-bf16 (unchanged from R4) ----------------
__global__ __launch_bounds__(640) void k_leaf(
    const int* __restrict__ x, const float* __restrict__ emb,
    const ushort_t* __restrict__ b1f, const ushort_t* __restrict__ b2f,
    const ushort_t* __restrict__ b3f, const float* __restrict__ bcat,
    const float* __restrict__ bp, const float* __restrict__ bx,
    float* __restrict__ h0, float* __restrict__ c0)
{
    __shared__ ushort_t ehi[36 * EST], elo[36 * EST];
    __shared__ ushort_t chi[32 * CST], clo[32 * CST];
    __shared__ ushort_t lhi[32 * LSU], llo[32 * LSU];

    const int b   = blockIdx.x;
    const int s0  = blockIdx.y * 32;
    const int tid = threadIdx.x;
    const int wv  = tid >> 6;
    const int lane = tid & 63;
    const int lc = lane & 15, lq = lane >> 4;

    for (int idx = tid; idx < 36 * 75; idx += 640) {
        int r = idx / 75, q = idx - r * 75;
        int sp = s0 - 2 + r;
        float4 v = make_float4(0.f, 0.f, 0.f, 0.f);
        if (sp >= 0 && sp < SS) {
            int tok = x[b * SS + sp];
            v = *reinterpret_cast<const float4*>(emb + (size_t)tok * EE + q * 4);
        }
        ushort_t h4[4], l4[4];
        split_bf16(v.x, h4[0], l4[0]); split_bf16(v.y, h4[1], l4[1]);
        split_bf16(v.z, h4[2], l4[2]); split_bf16(v.w, h4[3], l4[3]);
        *(ushort4*)&ehi[r * EST + q * 4] = make_ushort4(h4[0], h4[1], h4[2], h4[3]);
        *(ushort4*)&elo[r * EST + q * 4] = make_ushort4(l4[0], l4[1], l4[2], l4[3]);
    }
    for (int idx = tid; idx < 36 * 20; idx += 640) {
        int r = idx / 20, c = 300 + idx % 20;
        ehi[r * EST + c] = 0; elo[r * EST + c] = 0;
    }
    for (int idx = tid; idx < 32 * 16; idx += 640) {
        int r = idx / 16, c = 304 + idx % 16;
        chi[r * CST + c] = 0; clo[r * CST + c] = 0;
    }
    __syncthreads();

    {
        const bool has1 = (wv < 9);
        const int nt0 = wv, nt1 = wv + 10;
        const int kt01 = (nt1 < 12) ? 10 : 0;
        const int f0 = nt0 * 16 + lc;
        const int f1 = nt1 * 16 + lc;
        const float bv0 = bcat[f0];
        const float bv1 = (has1 && f1 < 300) ? bcat[f1] : 0.0f;
        f32x4 c00 = {bv0, bv0, bv0, bv0}, c01 = c00;
        f32x4 c10 = {bv1, bv1, bv1, bv1}, c11 = c10;
        const int ktstart = has1 ? (kt01 < 10 ? 0 : 10) : 10;
        for (int kt = ktstart; kt < 50; ++kt) {
            int t = kt / 10;
            int jj = (kt - t * 10) * 32 + (lq << 3);
            int ra = lc + t;
            s16x8 A0h = *(const s16x8*)&ehi[ra * EST + jj];
            s16x8 A0l = *(const s16x8*)&elo[ra * EST + jj];
            s16x8 A1h = *(const s16x8*)&ehi[(ra + 16) * EST + jj];
            s16x8 A1l = *(const s16x8*)&elo[(ra + 16) * EST + jj];
            if (kt >= 10) {
                const ushort_t* p8 = b1f + ((size_t)b1_tile(nt0, kt) * 64 + lane) * 16;
                s16x8 Bh = *(const s16x8*)p8;
                s16x8 Bl = *(const s16x8*)(p8 + 8);
                c00 = MFMA(A0h, Bh, c00, 0, 0, 0);
                c00 = MFMA(A0h, Bl, c00, 0, 0, 0);
                c00 = MFMA(A0l, Bh, c00, 0, 0, 0);
                c01 = MFMA(A1h, Bh, c01, 0, 0, 0);
                c01 = MFMA(A1h, Bl, c01, 0, 0, 0);
                c01 = MFMA(A1l, Bh, c01, 0, 0, 0);
            }
            if (has1 && kt >= kt01) {
                const ushort_t* p8 = b1f + ((size_t)b1_tile(nt1, kt) * 64 + lane) * 16;
                s16x8 Bh = *(const s16x8*)p8;
                s16x8 Bl = *(const s16x8*)(p8 + 8);
                c10 = MFMA(A0h, Bh, c10, 0, 0, 0);
                c10 = MFMA(A0h, Bl, c10, 0, 0, 0);
                c10 = MFMA(A0l, Bh, c10, 0, 0, 0);
                c11 = MFMA(A1h, Bh, c11, 0, 0, 0);
                c11 = MFMA(A1h, Bl, c11, 0, 0, 0);
                c11 = MFMA(A1l, Bh, c11, 0, 0, 0);
            }
        }
        #pragma unroll
        for (int r = 0; r < 4; ++r) {
            int p = lq * 4 + r;
            ushort_t hu, lu;
            split_bf16(fmaxf(c00[r], 0.0f), hu, lu);
            chi[p * CST + f0] = hu; clo[p * CST + f0] = lu;
            split_bf16(fmaxf(c01[r], 0.0f), hu, lu);
            chi[(p + 16) * CST + f0] = hu; clo[(p + 16) * CST + f0] = lu;
            if (has1) {
                split_bf16(fmaxf(c10[r], 0.0f), hu, lu);
                chi[p * CST + f1] = hu; clo[p * CST + f1] = lu;
                split_bf16(fmaxf(c11[r], 0.0f), hu, lu);
                chi[(p + 16) * CST + f1] = hu; clo[(p + 16) * CST + f1] = lu;
            }
        }
    }
    __syncthreads();

    {
        const int hcol = wv * 16 + lc;
        const float bv = (hcol < 150) ? bp[hcol] : 0.0f;
        f32x4 d0 = {bv, bv, bv, bv}, d1 = d0;
        for (int kt = 0; kt < 20; ++kt) {
            s16x8 A0h, A0l, A1h, A1l;
            if (kt < 10) {
                int col = kt * 32 + (lq << 3);
                int ra = lc + 2;
                A0h = *(const s16x8*)&ehi[ra * EST + col];
                A0l = *(const s16x8*)&elo[ra * EST + col];
                A1h = *(const s16x8*)&ehi[(ra + 16) * EST + col];
                A1l = *(const s16x8*)&elo[(ra + 16) * EST + col];
            } else {
                int col = (kt - 10) * 32 + (lq << 3);
                A0h = *(const s16x8*)&chi[lc * CST + col];
                A0l = *(const s16x8*)&clo[lc * CST + col];
                A1h = *(const s16x8*)&chi[(lc + 16) * CST + col];
                A1l = *(const s16x8*)&clo[(lc + 16) * CST + col];
            }
            const ushort_t* p8 = b2f + ((size_t)(wv * 20 + kt) * 64 + lane) * 16;
            s16x8 Bh = *(const s16x8*)p8;
            s16x8 Bl = *(const s16x8*)(p8 + 8);
            d0 = MFMA(A0h, Bh, d0, 0, 0, 0);
            d0 = MFMA(A0h, Bl, d0, 0, 0, 0);
            d0 = MFMA(A0l, Bh, d0, 0, 0, 0);
            d1 = MFMA(A1h, Bh, d1, 0, 0, 0);
            d1 = MFMA(A1h, Bl, d1, 0, 0, 0);
            d1 = MFMA(A1l, Bh, d1, 0, 0, 0);
        }
        #pragma unroll
        for (int r = 0; r < 4; ++r) {
            int p = lq * 4 + r;
            ushort_t hu, lu;
            split_bf16(d0[r], hu, lu);
            lhi[p * LSU + hcol] = hu; llo[p * LSU + hcol] = lu;
            split_bf16(d1[r], hu, lu);
            lhi[(p + 16) * LSU + hcol] = hu; llo[(p + 16) * LSU + hcol] = lu;
        }
    }
    __syncthreads();

    {
        const int hc = wv * 16 + lc;
        const bool hval = (hc < 150);
        const float bi = hval ? bx[hc] : 0.0f;
        const float bo = hval ? bx[450 + hc] : 0.0f;
        const float bu = hval ? bx[600 + hc] : 0.0f;
        f32x4 gi0 = {bi, bi, bi, bi}, gi1 = gi0;
        f32x4 go0 = {bo, bo, bo, bo}, go1 = go0;
        f32x4 gu0 = {bu, bu, bu, bu}, gu1 = gu0;
        for (int kt = 0; kt < 5; ++kt) {
            int col = kt * 32 + (lq << 3);
            s16x8 A0h = *(const s16x8*)&lhi[lc * LSU + col];
            s16x8 A0l = *(const s16x8*)&llo[lc * LSU + col];
            s16x8 A1h = *(const s16x8*)&lhi[(lc + 16) * LSU + col];
            s16x8 A1l = *(const s16x8*)&llo[(lc + 16) * LSU + col];
            const ushort_t* p8i = b3f + ((size_t)((0 + wv) * 5 + kt) * 64 + lane) * 16;
            const ushort_t* p8o = b3f + ((size_t)((10 + wv) * 5 + kt) * 64 + lane) * 16;
            const ushort_t* p8u = b3f + ((size_t)((20 + wv) * 5 + kt) * 64 + lane) * 16;
            s16x8 Bh, Bl;
            Bh = *(const s16x8*)p8i; Bl = *(const s16x8*)(p8i + 8);
            gi0 = MFMA(A0h, Bh, gi0, 0, 0, 0); gi0 = MFMA(A0h, Bl, gi0, 0, 0, 0); gi0 = MFMA(A0l, Bh, gi0, 0, 0, 0);
            gi1 = MFMA(A1h, Bh, gi1, 0, 0, 0); gi1 = MFMA(A1h, Bl, gi1, 0, 0, 0); gi1 = MFMA(A1l, Bh, gi1, 0, 0, 0);
            Bh = *(const s16x8*)p8o; Bl = *(const s16x8*)(p8o + 8);
            go0 = MFMA(A0h, Bh, go0, 0, 0, 0); go0 = MFMA(A0h, Bl, go0, 0, 0, 0); go0 = MFMA(A0l, Bh, go0, 0, 0, 0);
            go1 = MFMA(A1h, Bh, go1, 0, 0, 0); go1 = MFMA(A1h, Bl, go1, 0, 0, 0); go1 = MFMA(A1l, Bh, go1, 0, 0, 0);
            Bh = *(const s16x8*)p8u; Bl = *(const s16x8*)(p8u + 8);
            gu0 = MFMA(A0h, Bh, gu0, 0, 0, 0); gu0 = MFMA(A0h, Bl, gu0, 0, 0, 0); gu0 = MFMA(A0l, Bh, gu0, 0, 0, 0);
            gu1 = MFMA(A1h, Bh, gu1, 0, 0, 0); gu1 = MFMA(A1h, Bl, gu1, 0, 0, 0); gu1 = MFMA(A1l, Bh, gu1, 0, 0, 0);
        }
        if (hval) {
            #pragma unroll
            for (int r = 0; r < 4; ++r) {
                {
                    int s = s0 + lq * 4 + r;
                    float iv = sigmoidf_(gi0[r]), ov = sigmoidf_(go0[r]), uv = tanh_fast(gu0[r]);
                    float cc = iv * uv;
                    size_t o = ((size_t)b * SS + s) * HH + hc;
                    h0[o] = ov * tanh_fast(cc);
                    c0[o] = cc;
                }
                {
                    int s = s0 + 16 + lq * 4 + r;
                    float iv = sigmoidf_(gi1[r]), ov = sigmoidf_(go1[r]), uv = tanh_fast(gu1[r]);
                    float cc = iv * uv;
                    size_t o = ((size_t)b * SS + s) * HH + hc;
                    h0[o] = ov * tanh_fast(cc);
                    c0[o] = cc;
                }
            }
        }
    }
}

// ---------------- k_tree2: MFMA split-bf16 tree level, 32 nodes/block, 10 waves -------
// A[32][320]: [lh 150 |pad| rh 150 |pad]; B = utf tiles [(g*10+ht)*10+kt].
// Wave = h-tile; accumulates all 5 gates in-register -> cell in-register.
__global__ __launch_bounds__(640) void k_tree2(
    const float* __restrict__ in_h, const float* __restrict__ in_c,
    float* __restrict__ out_h, float* __restrict__ out_c,
    int n_out,
    const ushort_t* __restrict__ utf, const float* __restrict__ bx)
{
    __shared__ ushort_t ahi[32 * AST], alo[32 * AST];

    const int b   = blockIdx.x;
    const int m0  = blockIdx.y * 32;
    const int tid = threadIdx.x;
    const int wv  = tid >> 6, lane = tid & 63;
    const int lc  = lane & 15, lq = lane >> 4;
    const int n_in = n_out * 2;

    // stage A: 64 child rows (contiguous 9600 floats), split hi/lo
    const float* src = in_h + ((size_t)b * n_in + 2 * m0) * HH;
    for (int idx = tid; idx < 4800; idx += 640) {
        float2 v = *(const float2*)(src + idx * 2);
        int e = idx * 2;
        int r = e / 150, k = e - r * 150;
        int base = (r >> 1) * AST + (r & 1) * 160 + k;
        ushort_t ha, la, hb, lb;
        split_bf16(v.x, ha, la);
        split_bf16(v.y, hb, lb);
        ahi[base] = ha; ahi[base + 1] = hb;
        alo[base] = la; alo[base + 1] = lb;
    }
    // zero pads: k = 150..159 and 310..319 for all 32 rows (exactly 640 entries)
    {
        int m = tid / 20, j = tid - (tid / 20) * 20;
        int k = (j < 10) ? (150 + j) : (310 + j - 10);
        ahi[m * AST + k] = 0; alo[m * AST + k] = 0;
    }
    __syncthreads();

    const int hc = wv * 16 + lc;
    const bool hval = (hc < 150);
    const float bi = hval ? bx[hc] : 0.f;
    const float bl = hval ? bx[150 + hc] : 0.f;
    const float br = hval ? bx[300 + hc] : 0.f;
    const float bo = hval ? bx[450 + hc] : 0.f;
    const float bu = hval ? bx[600 + hc] : 0.f;
    f32x4 ai0 = {bi, bi, bi, bi}, ai1 = ai0;
    f32x4 al0 = {bl, bl, bl, bl}, al1 = al0;
    f32x4 ar0 = {br, br, br, br}, ar1 = ar0;
    f32x4 ao0 = {bo, bo, bo, bo}, ao1 = ao0;
    f32x4 au0 = {bu, bu, bu, bu}, au1 = au0;

    const size_t gstride = (size_t)100 * 1024;   // 100 tiles * 1024 ushorts
    for (int kt = 0; kt < 10; ++kt) {
        int col = kt * 32 + (lq << 3);
        s16x8 A0h = *(const s16x8*)&ahi[lc * AST + col];
        s16x8 A0l = *(const s16x8*)&alo[lc * AST + col];
        s16x8 A1h = *(const s16x8*)&ahi[(lc + 16) * AST + col];
        s16x8 A1l = *(const s16x8*)&alo[(lc + 16) * AST + col];
        const ushort_t* pb = utf + ((size_t)(wv * 10 + kt) * 64 + lane) * 16;
        s16x8 Bh, Bl;
        Bh = *(const s16x8*)pb; Bl = *(const s16x8*)(pb + 8);
        ai0 = MFMA(A0h, Bh, ai0, 0, 0, 0); ai0 = MFMA(A0h, Bl, ai0, 0, 0, 0); ai0 = MFMA(A0l, Bh, ai0, 0, 0, 0);
        ai1 = MFMA(A1h, Bh, ai1, 0, 0, 0); ai1 = MFMA(A1h, Bl, ai1, 0, 0, 0); ai1 = MFMA(A1l, Bh, ai1, 0, 0, 0);
        pb += gstride;
        Bh = *(const s16x8*)pb; Bl = *(const s16x8*)(pb + 8);
        al0 = MFMA(A0h, Bh, al0, 0, 0, 0); al0 = MFMA(A0h, Bl, al0, 0, 0, 0); al0 = MFMA(A0l, Bh, al0, 0, 0, 0);
        al1 = MFMA(A1h, Bh, al1, 0, 0, 0); al1 = MFMA(A1h, Bl, al1, 0, 0, 0); al1 = MFMA(A1l, Bh, al1, 0, 0, 0);
        pb += gstride;
        Bh = *(const s16x8*)pb; Bl = *(const s16x8*)(pb + 8);
        ar0 = MFMA(A0h, Bh, ar0, 0, 0, 0); ar0 = MFMA(A0h, Bl, ar0, 0, 0, 0); ar0 = MFMA(A0l, Bh, ar0, 0, 0, 0);
        ar1 = MFMA(A1h, Bh, ar1, 0, 0, 0); ar1 = MFMA(A1h, Bl, ar1, 0, 0, 0); ar1 = MFMA(A1l, Bh, ar1, 0, 0, 0);
        pb += gstride;
        Bh = *(const s16x8*)pb; Bl = *(const s16x8*)(pb + 8);
        ao0 = MFMA(A0h, Bh, ao0, 0, 0, 0); ao0 = MFMA(A0h, Bl, ao0, 0, 0, 0); ao0 = MFMA(A0l, Bh, ao0, 0, 0, 0);
        ao1 = MFMA(A1h, Bh, ao1, 0, 0, 0); ao1 = MFMA(A1h, Bl, ao1, 0, 0, 0); ao1 = MFMA(A1l, Bh, ao1, 0, 0, 0);
        pb += gstride;
        Bh = *(const s16x8*)pb; Bl = *(const s16x8*)(pb + 8);
        au0 = MFMA(A0h, Bh, au0, 0, 0, 0); au0 = MFMA(A0h, Bl, au0, 0, 0, 0); au0 = MFMA(A0l, Bh, au0, 0, 0, 0);
        au1 = MFMA(A1h, Bh, au1, 0, 0, 0); au1 = MFMA(A1h, Bl, au1, 0, 0, 0); au1 = MFMA(A1l, Bh, au1, 0, 0, 0);
    }

    if (hval) {
        #pragma unroll
        for (int r = 0; r < 4; ++r) {
            int ml = lq * 4 + r;
            {
                int m = m0 + ml;
                size_t cb = ((size_t)b * n_in + 2 * m) * HH + hc;
                float iv = sigmoidf_(ai0[r]);
                float fl = sigmoidf_(al0[r]);
                float fr = sigmoidf_(ar0[r]);
                float ov = sigmoidf_(ao0[r]);
                float uv = tanh_fast(au0[r]);
                float cc = iv * uv + fl * in_c[cb] + fr * in_c[cb + HH];
                size_t ob = ((size_t)b * n_out + m) * HH + hc;
                out_h[ob] = ov * tanh_fast(cc);
                out_c[ob] = cc;
            }
            {
                int m = m0 + 16 + ml;
                size_t cb = ((size_t)b * n_in + 2 * m) * HH + hc;
                float iv = sigmoidf_(ai1[r]);
                float fl = sigmoidf_(al1[r]);
                float fr = sigmoidf_(ar1[r]);
                float ov = sigmoidf_(ao1[r]);
                float uv = tanh_fast(au1[r]);
                float cc = iv * uv + fl * in_c[cb] + fr * in_c[cb + HH];
                size_t ob = ((size_t)b * n_out + m) * HH + hc;
                out_h[ob] = ov * tanh_fast(cc);
                out_c[ob] = cc;
            }
        }
    }
}

// ---------------- k_tail: levels 16..1 in LDS + head MLP (fp32, unchanged) ---------
__global__ __launch_bounds__(384) void k_tail(
    const float* __restrict__ in_h, const float* __restrict__ in_c,
    const float* __restrict__ ULT, const float* __restrict__ URT,
    const float* __restrict__ bx,
    const float* __restrict__ W1, const float* __restrict__ b1,
    const float* __restrict__ W2, const float* __restrict__ b2,
    float* __restrict__ out)
{
    __shared__ float pool[96 * LST + TN * GS];
    float* Ah = pool;
    float* Ac = Ah + 32 * LST;
    float* Bh = Ac + 32 * LST;
    float* Bc = Bh + 16 * LST;
    float* gs = Bc + 16 * LST;
    __shared__ float z_s[80];

    const int b   = blockIdx.x;
    const int tid = threadIdx.x;

    for (int idx = tid; idx < 32 * HH; idx += 384) {
        int p = idx / HH, j = idx - p * HH;
        size_t base = ((size_t)b * 32 + p) * HH + j;
        Ah[p * LST + j] = in_h[base];
        Ac[p * LST + j] = in_c[base];
    }

    const int o1 = tid, o2 = tid + 384;
    const int o2c = (o2 < 752) ? o2 : 751;
    const float bx1 = bx[o1];
    const float bx2 = (o2 < 750) ? bx[o2] : 0.0f;
    const float* ul1 = ULT + o1; const float* ur1 = URT + o1;
    const float* ul2 = ULT + o2c; const float* ur2 = URT + o2c;

    float* curh = Ah; float* curc = Ac;
    float* nxth = Bh; float* nxtc = Bc;

    for (int n = 16; n >= 1; n >>= 1) {
        __syncthreads();
        {
            float a1[TN], a2[TN];
            #pragma unroll
            for (int m = 0; m < TN; ++m) { a1[m] = bx1; a2[m] = bx2; }
            for (int j = 0; j < 150; j += 2) {
                int r0 = j * UST, r1 = (j + 1) * UST;
                float wl1a = ul1[r0], wl1b = ul1[r1];
                float wr1a = ur1[r0], wr1b = ur1[r1];
                float wl2a = ul2[r0], wl2b = ul2[r1];
                float wr2a = ur2[r0], wr2b = ur2[r1];
                #pragma unroll
                for (int m = 0; m < TN; ++m) {
                    float2 lv = *(const float2*)(curh + (2 * m) * LST + j);
                    float2 rv = *(const float2*)(curh + (2 * m + 1) * LST + j);
                    a1[m] += lv.x * wl1a + lv.y * wl1b + rv.x * wr1a + rv.y * wr1b;
                    a2[m] += lv.x * wl2a + lv.y * wl2b + rv.x * wr2a + rv.y * wr2b;
                }
            }
            #pragma unroll
            for (int m = 0; m < TN; ++m) {
                if (m < n) {
                    gs[m * GS + o1] = a1[m];
                    if (o2 < 750) gs[m * GS + o2] = a2[m];
                }
            }
        }
        __syncthreads();
        for (int idx = tid; idx < n * HH; idx += 384) {
            int m = idx / HH, h = idx - m * HH;
            float iv = sigmoidf_(gs[m * GS + h]);
            float fL = sigmoidf_(gs[m * GS + 150 + h]);
            float fR = sigmoidf_(gs[m * GS + 300 + h]);
            float ov = sigmoidf_(gs[m * GS + 450 + h]);
            float uv = tanh_fast(gs[m * GS + 600 + h]);
            float cc = iv * uv + fL * curc[2 * m * LST + h] + fR * curc[(2 * m + 1) * LST + h];
            nxth[m * LST + h] = ov * tanh_fast(cc);
            nxtc[m * LST + h] = cc;
        }
        float* t;
        t = curh; curh = nxth; nxth = t;
        t = curc; curc = nxtc; nxtc = t;
    }
    __syncthreads();

    if (tid < 75) {
        const float* w = W1 + (size_t)tid * 150;
        float acc = b1[tid];
        for (int j = 0; j < 150; ++j) acc += curh[j] * w[j];
        z_s[tid] = fmaxf(acc, 0.0f);
    }
    __syncthreads();
    if (tid < 3) {
        const float* w = W2 + (size_t)tid * 75;
        float acc = b2[tid];
        for (int j = 0; j < 75; ++j) acc += z_s[j] * w[j];
        out[(size_t)b * 3 + tid] = acc;
    }
}

extern "C" void kernel_launch(void* const* d_in, const int* in_sizes, int n_in,
                              void* d_out, int out_size, void* d_ws, size_t ws_size,
                              hipStream_t stream) {
    const int*   x   = (const int*)  d_in[0];
    const float* emb = (const float*)d_in[1];
    const float* w3  = (const float*)d_in[2];
    const float* b3  = (const float*)d_in[3];
    const float* w4  = (const float*)d_in[4];
    const float* b4  = (const float*)d_in[5];
    const float* w5  = (const float*)d_in[6];
    const float* b5  = (const float*)d_in[7];
    const float* Wp  = (const float*)d_in[8];
    const float* bp  = (const float*)d_in[9];
    const float* Wx  = (const float*)d_in[10];
    const float* bx  = (const float*)d_in[11];
    const float* UL  = (const float*)d_in[12];
    const float* UR  = (const float*)d_in[13];
    const float* W1  = (const float*)d_in[14];
    const float* b1  = (const float*)d_in[15];
    const float* W2  = (const float*)d_in[16];
    const float* b2  = (const float*)d_in[17];
    float* out = (float*)d_out;

    char* wsb = (char*)d_ws;
    const ushort_t* b1f = (const ushort_t*)(wsb + OB_B1);
    const ushort_t* b2f = (const ushort_t*)(wsb + OB_B2);
    const ushort_t* b3f = (const ushort_t*)(wsb + OB_B3);
    const ushort_t* utf = (const ushort_t*)(wsb + OB_UT);
    const float* bcat = (const float*)(wsb + OB_BC);
    const float* ULT  = (const float*)(wsb + OB_ULT);
    const float* URT  = (const float*)(wsb + OB_URT);
    float* h0 = (float*)(wsb + OB_H0);
    float* c0 = (float*)(wsb + OB_C0);
    float* h1 = (float*)(wsb + OB_H1);
    float* c1 = (float*)(wsb + OB_C1);

    {
        int total = 830 * 64 + 200 * 64 + 150 * 64 + 500 * 64 + 304 + 2 * 150 * UST;
        k_prep<<<(total + 255) / 256, 256, 0, stream>>>(
            w3, b3, w4, b4, w5, b5, Wp, Wx, UL, UR, wsb);
    }

    k_leaf<<<dim3(BB, SS / 32), 640, 0, stream>>>(
        x, emb, b1f, b2f, b3f, bcat, bp, bx, h0, c0);

    k_tree2<<<dim3(BB, 8), 640, 0, stream>>>(h0, c0, h1, c1, 256, utf, bx);
    k_tree2<<<dim3(BB, 4), 640, 0, stream>>>(h1, c1, h0, c0, 128, utf, bx);
    k_tree2<<<dim3(BB, 2), 640, 0, stream>>>(h0, c0, h1, c1,  64, utf, bx);
    k_tree2<<<dim3(BB, 1), 640, 0, stream>>>(h1, c1, h0, c0,  32, utf, bx);

    k_tail<<<BB, 384, 0, stream>>>(h0, c0, ULT, URT, bx, W1, b1, W2, b2, out);
}